// Round 11
// baseline (594.362 us; speedup 1.0000x reference)
//
#include <hip/hip_runtime.h>
#include <math.h>

#define BB 16
#define NN 512
#define KNN 8
#define SEQ 12
#define TQ 8            // knn: threads per query
#define QB 32           // knn: queries per block (TQ*QB = 256 threads)
#define PB 16           // cells: points per block

typedef __attribute__((ext_vector_type(8))) short bf8_t;   // 8 bf16 (4 VGPRs)
typedef __attribute__((ext_vector_type(4))) float f4_t;    // MFMA acc

__device__ __forceinline__ ushort f2b(float x) {           // fp32 -> bf16 RNE
    uint u = __float_as_uint(x);
    return (ushort)((u + 0x7fffu + ((u >> 16) & 1u)) >> 16);
}
__device__ __forceinline__ float b2f(ushort h) {
    return __uint_as_float((uint)h << 16);
}

// ---------------------------------------------------------------------------
// KNN standalone (warmup only, warm=1 path) — unchanged, verified correct.
// ---------------------------------------------------------------------------
__global__ __launch_bounds__(256) void knn_kernel(
        const float* __restrict__ xq, int xq_bs,
        const float* __restrict__ xs, int xs_bs,
        int* __restrict__ idx1, int* __restrict__ idx2, int* __restrict__ idx3,
        float r2a, float r2b, float r2c, int warm) {
    __shared__ float s[NN * 3 + NN / 64];
    __shared__ float cd[QB][TQ][KNN + 1];
    __shared__ int   ci[QB][TQ][KNN + 1];
    int b = blockIdx.y;
    const float* xqp; const float* xsp; long iofs;
    if (warm) {
        int z = blockIdx.z;
        int qz = z < 5 ? z : 5;
        int sz = z - 1 < 0 ? 0 : z - 1;
        xqp = xq + (long)qz * NN * 3;
        xsp = xq + (long)sz * NN * 3;
        xs_bs = xq_bs;
        iofs = (long)z * BB * NN * KNN;
    } else {
        xqp = xq; xsp = xs; iofs = 0;
    }

    for (int j = threadIdx.x; j < NN; j += 256) {
        const float* p = xsp + (long)b * xs_bs + j * 3;
        int o = 3 * j + (j >> 6);
        s[o + 0] = p[0]; s[o + 1] = p[1]; s[o + 2] = p[2];
    }
    __syncthreads();

    int qi  = threadIdx.x / TQ;
    int sub = threadIdx.x % TQ;
    int n = blockIdx.x * QB + qi;
    const float* q = xqp + (long)b * xq_bs + n * 3;
    float qx = q[0], qy = q[1], qz2 = q[2];

    float bd[KNN];
    int   bi[KNN];
#pragma unroll
    for (int k = 0; k < KNN; ++k) { bd[k] = 1e30f; bi[k] = 0; }

    int j0 = sub * (NN / TQ);
    int sbase = 3 * j0 + sub;
#pragma unroll 4
    for (int jj = 0; jj < NN / TQ; ++jj) {
        float dx = s[sbase + 3 * jj + 0] - qx;
        float dy = s[sbase + 3 * jj + 1] - qy;
        float dz = s[sbase + 3 * jj + 2] - qz2;
        float d2 = fmaf(dx, dx, fmaf(dy, dy, dz * dz));
        if (d2 < bd[KNN - 1]) {
            bd[KNN - 1] = d2; bi[KNN - 1] = j0 + jj;
#pragma unroll
            for (int k = KNN - 1; k >= 1; --k) {
                if (bd[k] < bd[k - 1]) {
                    float td = bd[k]; bd[k] = bd[k - 1]; bd[k - 1] = td;
                    int   ti = bi[k]; bi[k] = bi[k - 1]; bi[k - 1] = ti;
                }
            }
        }
    }

#pragma unroll
    for (int k = 0; k < KNN; ++k) { cd[qi][sub][k] = bd[k]; ci[qi][sub][k] = bi[k]; }
    cd[qi][sub][KNN] = 1e30f; ci[qi][sub][KNN] = 0x7fffffff;
    __syncthreads();

    for (int stride = TQ / 2; stride >= 1; stride >>= 1) {
        if (sub < stride) {
            float rd[KNN]; int ri[KNN];
            int ia = 0, ib = 0;
#pragma unroll
            for (int k = 0; k < KNN; ++k) {
                float da = cd[qi][sub][ia], db = cd[qi][sub + stride][ib];
                int   ja = ci[qi][sub][ia], jb = ci[qi][sub + stride][ib];
                bool ta = (da < db) || (da == db && ja < jb);
                rd[k] = ta ? da : db; ri[k] = ta ? ja : jb;
                ia += ta ? 1 : 0; ib += ta ? 0 : 1;
            }
#pragma unroll
            for (int k = 0; k < KNN; ++k) { cd[qi][sub][k] = rd[k]; ci[qi][sub][k] = ri[k]; }
        }
        __syncthreads();
    }

    if (sub == 0) {
        long base = iofs + ((long)(b * NN + n)) * KNN;
        int i0 = ci[qi][0][0];
#pragma unroll
        for (int k = 0; k < KNN; ++k) {
            float d = cd[qi][0][k]; int j = ci[qi][0][k];
            idx1[base + k] = (d <= r2a) ? j : i0;
            idx2[base + k] = (d <= r2b) ? j : i0;
            idx3[base + k] = (d <= r2c) ? j : i0;
        }
    }
}

// knn core as device function (for the fused gemmG+knn dispatch)
__device__ void knn_core(const float* __restrict__ xq, int xq_bs,
                         const float* __restrict__ xs, int xs_bs,
                         int* __restrict__ idx1, int* __restrict__ idx2,
                         int* __restrict__ idx3,
                         float r2a, float r2b, float r2c,
                         int bx, int b, int tid, char* smem) {
    float* s  = (float*)smem;            // [NN*3 + NN/64] = 1544 f
    float* cd = s + 1544;                // [32][8][9]
    int*   ci = (int*)(cd + 2304);       // [32][8][9]

    for (int j = tid; j < NN; j += 256) {
        const float* p = xs + (long)b * xs_bs + j * 3;
        int o = 3 * j + (j >> 6);
        s[o + 0] = p[0]; s[o + 1] = p[1]; s[o + 2] = p[2];
    }
    __syncthreads();

    int qi = tid / TQ, sub = tid % TQ;
    int n = bx * QB + qi;
    const float* q = xq + (long)b * xq_bs + n * 3;
    float qx = q[0], qy = q[1], qz2 = q[2];

    float bd[KNN]; int bi[KNN];
#pragma unroll
    for (int k = 0; k < KNN; ++k) { bd[k] = 1e30f; bi[k] = 0; }

    int j0 = sub * (NN / TQ);
    int sbase = 3 * j0 + sub;
#pragma unroll 4
    for (int jj = 0; jj < NN / TQ; ++jj) {
        float dx = s[sbase + 3 * jj + 0] - qx;
        float dy = s[sbase + 3 * jj + 1] - qy;
        float dz = s[sbase + 3 * jj + 2] - qz2;
        float d2 = fmaf(dx, dx, fmaf(dy, dy, dz * dz));
        if (d2 < bd[KNN - 1]) {
            bd[KNN - 1] = d2; bi[KNN - 1] = j0 + jj;
#pragma unroll
            for (int k = KNN - 1; k >= 1; --k) {
                if (bd[k] < bd[k - 1]) {
                    float td = bd[k]; bd[k] = bd[k - 1]; bd[k - 1] = td;
                    int   ti = bi[k]; bi[k] = bi[k - 1]; bi[k - 1] = ti;
                }
            }
        }
    }

    int b9 = (qi * 8 + sub) * 9;
#pragma unroll
    for (int k = 0; k < KNN; ++k) { cd[b9 + k] = bd[k]; ci[b9 + k] = bi[k]; }
    cd[b9 + KNN] = 1e30f; ci[b9 + KNN] = 0x7fffffff;
    __syncthreads();

    for (int stride = TQ / 2; stride >= 1; stride >>= 1) {
        if (sub < stride) {
            int a9 = (qi * 8 + sub) * 9, c9 = (qi * 8 + sub + stride) * 9;
            float rd[KNN]; int ri[KNN];
            int ia = 0, ib = 0;
#pragma unroll
            for (int k = 0; k < KNN; ++k) {
                float da = cd[a9 + ia], db = cd[c9 + ib];
                int   ja = ci[a9 + ia], jb = ci[c9 + ib];
                bool ta = (da < db) || (da == db && ja < jb);
                rd[k] = ta ? da : db; ri[k] = ta ? ja : jb;
                ia += ta ? 1 : 0; ib += ta ? 0 : 1;
            }
#pragma unroll
            for (int k = 0; k < KNN; ++k) { cd[a9 + k] = rd[k]; ci[a9 + k] = ri[k]; }
        }
        __syncthreads();
    }

    if (sub == 0) {
        int a9 = (qi * 8) * 9;
        long base = ((long)(b * NN + n)) * KNN;
        int i0 = ci[a9];
#pragma unroll
        for (int k = 0; k < KNN; ++k) {
            float d = cd[a9 + k]; int j = ci[a9 + k];
            idx1[base + k] = (d <= r2a) ? j : i0;
            idx2[base + k] = (d <= r2b) ? j : i0;
            idx3[base + k] = (d <= r2c) ? j : i0;
        }
    }
}

// ---------------------------------------------------------------------------
// One-time weight conversion to transposed split-bf16.
// ---------------------------------------------------------------------------
__global__ __launch_bounds__(256) void convW_kernel(
        const float* __restrict__ W1, const float* __restrict__ W2,
        const float* __restrict__ W3, const float* __restrict__ Wm,
        ushort* __restrict__ w1h, ushort* __restrict__ w1l,
        ushort* __restrict__ w2h, ushort* __restrict__ w2l,
        ushort* __restrict__ w3h, ushort* __restrict__ w3l,
        ushort* __restrict__ w2fh, ushort* __restrict__ w2fl,
        ushort* __restrict__ w3fh, ushort* __restrict__ w3fl,
        ushort* __restrict__ wmh, ushort* __restrict__ wml) {
    int t = blockIdx.x * 256 + threadIdx.x;
    float v; ushort* ph; ushort* pl; int idx;
    if (t < 4096)        { int n = t >> 6, k = t & 63;
        v = W1[(3 + k) * 64 + n];   ph = w1h;  pl = w1l;  idx = t; }
    else if (t < 20480)  { int u = t - 4096, n = u >> 7, k = u & 127;
        v = W2[(67 + k) * 128 + n]; ph = w2h;  pl = w2l;  idx = u; }
    else if (t < 86016)  { int u = t - 20480, n = u >> 8, k = u & 255;
        v = W3[(131 + k) * 256 + n]; ph = w3h; pl = w3l;  idx = u; }
    else if (t < 94208)  { int u = t - 86016, n = u >> 6, k = u & 63;
        v = W2[(3 + k) * 128 + n];  ph = w2fh; pl = w2fl; idx = u; }
    else if (t < 126976) { int u = t - 94208, n = u >> 7, k = u & 127;
        v = W3[(3 + k) * 256 + n];  ph = w3fh; pl = w3fl; idx = u; }
    else if (t < 143360) { int u = t - 126976, n = u >> 8, k = u & 255;
        v = Wm[k * 64 + n];         ph = wmh;  pl = wml;  idx = u; }
    else return;
    ushort h = f2b(v);
    ph[idx] = h; pl[idx] = f2b(v - b2f(h));
}

// ---------------------------------------------------------------------------
// Kernel A: combines on VALU, bases/head on MFMA with LDS-staged split-bf16
// activations (splits computed once in the combine phases — no per-wave
// redundant cvt). LDS pool with lifetime overlays (44.5 KB -> 3 blocks/CU).
// XCD-affinity block swizzle (batch b -> XCD b/2).
// ---------------------------------------------------------------------------
template<bool FIRST>
__global__ __launch_bounds__(512, 4) void cells_kernel(
        const float* __restrict__ xq, int xq_bs,
        const float* __restrict__ xs, int xs_bs,
        const int* __restrict__ i1, const int* __restrict__ i2,
        const int* __restrict__ i3,
        const float* __restrict__ G1p, const float* __restrict__ G2p,
        const float* __restrict__ G3p,
        ushort* __restrict__ s1h, ushort* __restrict__ s1l,
        ushort* __restrict__ s2h, ushort* __restrict__ s2l,
        ushort* __restrict__ s3h, ushort* __restrict__ s3l,
        const float* __restrict__ W1, const float* __restrict__ b1,
        const float* __restrict__ W2, const float* __restrict__ b2,
        const float* __restrict__ W3, const float* __restrict__ b3,
        const ushort* __restrict__ w2fh, const ushort* __restrict__ w2fl,
        const ushort* __restrict__ w3fh, const ushort* __restrict__ w3fl,
        const ushort* __restrict__ wmh, const ushort* __restrict__ wml,
        const float* __restrict__ bm,
        const float* __restrict__ Wl, const float* __restrict__ bl,
        float* __restrict__ xnext, int xn_bs, int do_head) {
    // LDS pool with lifetime overlays:
    //  [0,4608)      dsp [3][16][8][3] f        (P0->P5; hs overlays in P6)
    //  [4608,6144)   jss [3][16][8] i           (P0->P5)
    //  [6144,10752)  s1H/s1L [16][72] u each    (P1->P2; s3H overlays P5->P6)
    //  [10752,19200) s2s [16][132] f            (P2->P3; s3H/s3L overlay)
    //  [19200,27904) s2H/s2L [16][136] u each   (P3->P4; s3L overlays)
    //  [27904,44544) s3b [16][260] f            (P4->P5)
    __shared__ __attribute__((aligned(16))) char pool[44544];
    float*  dspf = (float*)pool;
    int*    jssp = (int*)(pool + 4608);
    ushort* s1H  = (ushort*)(pool + 6144);
    ushort* s1L  = (ushort*)(pool + 8448);
    float*  s2sp = (float*)(pool + 10752);
    ushort* s2H  = (ushort*)(pool + 19200);
    ushort* s2L  = (ushort*)(pool + 23552);
    float*  s3bp = (float*)(pool + 27904);
    ushort* s3H  = (ushort*)(pool + 6144);     // [16][264], overlays s1/s2s
    ushort* s3L  = (ushort*)(pool + 14592);    // overlays s2s tail/s2H
    float*  hsp  = (float*)pool;               // [16][64], overlays dsp (P6)

    const int tid = threadIdx.x;
    const int blk = blockIdx.x;          // 0..511
    const int xcd = blk & 7, slot = blk >> 3;
    const int b   = xcd * 2 + (slot >> 5);     // batch <-> XCD affinity
    const int n0  = (slot & 31) << 4;
    const long row0 = (long)b * NN + n0;
    const long bN = (long)b * NN;
    const int wv = tid >> 6, lane = tid & 63;
    const int fm = lane & 15, quad = lane >> 4;

    // P0: neighbor indices + displacements
    for (int t = tid; t < 3 * PB * KNN; t += 512) {
        int r = t >> 7, rem = t & 127, p = rem >> 3, k = rem & 7;
        const int* ix = (r == 0) ? i1 : ((r == 1) ? i2 : i3);
        int j = ix[(row0 + p) * KNN + k];
        jssp[t] = j;
        const float* sp = xs + (long)b * xs_bs + j * 3;
        const float* qp = xq + (long)b * xq_bs + (n0 + p) * 3;
        dspf[t * 3 + 0] = sp[0] - qp[0];
        dspf[t * 3 + 1] = sp[1] - qp[1];
        dspf[t * 3 + 2] = sp[2] - qp[2];
    }
    __syncthreads();

    // P1: cell1 combine -> split-bf16 to global + LDS
    {
        int co = tid & 63, q = tid >> 6;
        float g1r[2][KNN];
        if (!FIRST) {
#pragma unroll
            for (int r = 0; r < 2; ++r)
#pragma unroll
                for (int k = 0; k < KNN; ++k)
                    g1r[r][k] = G1p[(bN + jssp[(2 * q + r) * 8 + k]) * 64 + co];
        }
        float wx = W1[co], wy = W1[64 + co], wz = W1[128 + co];
        float bz = b1[co];
#pragma unroll
        for (int r = 0; r < 2; ++r) {
            int p = 2 * q + r;
            float acc = -1e30f;
#pragma unroll
            for (int k = 0; k < KNN; ++k) {
                int di = (p * 8 + k) * 3;
                float v = fmaf(dspf[di + 0], wx, bz);
                v = fmaf(dspf[di + 1], wy, v);
                v = fmaf(dspf[di + 2], wz, v);
                if (!FIRST) v += g1r[r][k];
                acc = fmaxf(acc, v);
            }
            ushort h = f2b(acc);
            ushort l = f2b(acc - b2f(h));
            s1h[(row0 + p) * 64 + co] = h;
            s1l[(row0 + p) * 64 + co] = l;
            s1H[p * 72 + co] = h;
            s1L[p * 72 + co] = l;
        }
    }
    __syncthreads();

    // G2 gathers prefetched (consumed in P3, hidden behind P2 MFMA)
    float4 g2r[KNN];
    {
        int c4 = tid & 31, g = tid >> 5;
        if (!FIRST) {
#pragma unroll
            for (int k = 0; k < KNN; ++k)
                g2r[k] = ((const float4*)G2p)[(bN + jssp[(16 + g) * 8 + k]) * 32 + c4];
        }
    }

    // P2: base2 = s1 @ W2f + b2 on MFMA (A-frags from LDS bf16, no cvt)
    {
        int col = wv * 16 + fm;
        float bz = b2[col];
        f4_t acc = {bz, bz, bz, bz};
#pragma unroll
        for (int k0 = 0; k0 < 64; k0 += 32) {
            bf8_t ah = *(const bf8_t*)(s1H + fm * 72 + k0 + quad * 8);
            bf8_t al = *(const bf8_t*)(s1L + fm * 72 + k0 + quad * 8);
            bf8_t bh = *(const bf8_t*)(w2fh + col * 64 + k0 + quad * 8);
            bf8_t bl = *(const bf8_t*)(w2fl + col * 64 + k0 + quad * 8);
            acc = __builtin_amdgcn_mfma_f32_16x16x32_bf16(ah, bh, acc, 0, 0, 0);
            acc = __builtin_amdgcn_mfma_f32_16x16x32_bf16(ah, bl, acc, 0, 0, 0);
            acc = __builtin_amdgcn_mfma_f32_16x16x32_bf16(al, bh, acc, 0, 0, 0);
        }
#pragma unroll
        for (int r = 0; r < 4; ++r) s2sp[(quad * 4 + r) * 132 + col] = acc[r];
    }
    __syncthreads();

    // P3: combine2 -> split-bf16 to global + LDS (split computed once here)
    {
        int c4 = tid & 31, g = tid >> 5;
        float4 bse = *(float4*)&s2sp[g * 132 + c4 * 4];
        float4 wx = ((const float4*)W2)[c4];
        float4 wy = ((const float4*)(W2 + 128))[c4];
        float4 wz = ((const float4*)(W2 + 256))[c4];
        float4 m = make_float4(-1e30f, -1e30f, -1e30f, -1e30f);
#pragma unroll
        for (int k = 0; k < KNN; ++k) {
            int di = ((16 + g) * 8 + k) * 3;
            float dx = dspf[di + 0], dy = dspf[di + 1], dz = dspf[di + 2];
            float4 v;
            v.x = fmaf(dz, wz.x, fmaf(dy, wy.x, fmaf(dx, wx.x, bse.x)));
            v.y = fmaf(dz, wz.y, fmaf(dy, wy.y, fmaf(dx, wx.y, bse.y)));
            v.z = fmaf(dz, wz.z, fmaf(dy, wy.z, fmaf(dx, wx.z, bse.z)));
            v.w = fmaf(dz, wz.w, fmaf(dy, wy.w, fmaf(dx, wx.w, bse.w)));
            if (!FIRST) {
                v.x += g2r[k].x; v.y += g2r[k].y;
                v.z += g2r[k].z; v.w += g2r[k].w;
            }
            m.x = fmaxf(m.x, v.x); m.y = fmaxf(m.y, v.y);
            m.z = fmaxf(m.z, v.z); m.w = fmaxf(m.w, v.w);
        }
        ushort4 mh, ml;
        mh.x = f2b(m.x); ml.x = f2b(m.x - b2f(mh.x));
        mh.y = f2b(m.y); ml.y = f2b(m.y - b2f(mh.y));
        mh.z = f2b(m.z); ml.z = f2b(m.z - b2f(mh.z));
        mh.w = f2b(m.w); ml.w = f2b(m.w - b2f(mh.w));
        *(ushort4*)&s2h[(row0 + g) * 128 + c4 * 4] = mh;
        *(ushort4*)&s2l[(row0 + g) * 128 + c4 * 4] = ml;
        *(ushort4*)(s2H + g * 136 + c4 * 4) = mh;
        *(ushort4*)(s2L + g * 136 + c4 * 4) = ml;
    }
    __syncthreads();

    // G3 gathers prefetched (consumed in P5, hidden behind P4 MFMA)
    float4 g3r[2][KNN];
    {
        int c4 = tid & 63, g = tid >> 6;
        if (!FIRST) {
#pragma unroll
            for (int r = 0; r < 2; ++r)
#pragma unroll
                for (int k = 0; k < KNN; ++k)
                    g3r[r][k] = ((const float4*)G3p)[(bN + jssp[(32 + 2 * g + r) * 8 + k]) * 64 + c4];
        }
    }

    // P4: base3 = s2 @ W3f + b3 on MFMA (A from LDS bf16)
    {
        int col0 = wv * 16 + fm, col1 = (wv + 8) * 16 + fm;
        float bz0 = b3[col0], bz1 = b3[col1];
        f4_t a0 = {bz0, bz0, bz0, bz0};
        f4_t a1 = {bz1, bz1, bz1, bz1};
#pragma unroll
        for (int k0 = 0; k0 < 128; k0 += 32) {
            bf8_t ah = *(const bf8_t*)(s2H + fm * 136 + k0 + quad * 8);
            bf8_t al = *(const bf8_t*)(s2L + fm * 136 + k0 + quad * 8);
            bf8_t b0h = *(const bf8_t*)(w3fh + col0 * 128 + k0 + quad * 8);
            bf8_t b0l = *(const bf8_t*)(w3fl + col0 * 128 + k0 + quad * 8);
            bf8_t b1h = *(const bf8_t*)(w3fh + col1 * 128 + k0 + quad * 8);
            bf8_t b1l = *(const bf8_t*)(w3fl + col1 * 128 + k0 + quad * 8);
            a0 = __builtin_amdgcn_mfma_f32_16x16x32_bf16(ah, b0h, a0, 0, 0, 0);
            a0 = __builtin_amdgcn_mfma_f32_16x16x32_bf16(ah, b0l, a0, 0, 0, 0);
            a0 = __builtin_amdgcn_mfma_f32_16x16x32_bf16(al, b0h, a0, 0, 0, 0);
            a1 = __builtin_amdgcn_mfma_f32_16x16x32_bf16(ah, b1h, a1, 0, 0, 0);
            a1 = __builtin_amdgcn_mfma_f32_16x16x32_bf16(ah, b1l, a1, 0, 0, 0);
            a1 = __builtin_amdgcn_mfma_f32_16x16x32_bf16(al, b1h, a1, 0, 0, 0);
        }
#pragma unroll
        for (int r = 0; r < 4; ++r) {
            s3bp[(quad * 4 + r) * 260 + col0] = a0[r];
            s3bp[(quad * 4 + r) * 260 + col1] = a1[r];
        }
    }
    __syncthreads();

    // P5: combine3 -> split-bf16 to global (+ LDS if head step)
    {
        int c4 = tid & 63, g = tid >> 6;
        float4 wx = ((const float4*)W3)[c4];
        float4 wy = ((const float4*)(W3 + 256))[c4];
        float4 wz = ((const float4*)(W3 + 512))[c4];
#pragma unroll
        for (int r = 0; r < 2; ++r) {
            int p = 2 * g + r;
            float4 bse = *(float4*)&s3bp[p * 260 + c4 * 4];
            float4 m = make_float4(-1e30f, -1e30f, -1e30f, -1e30f);
#pragma unroll
            for (int k = 0; k < KNN; ++k) {
                int di = ((32 + p) * 8 + k) * 3;
                float dx = dspf[di + 0], dy = dspf[di + 1], dz = dspf[di + 2];
                float4 v;
                v.x = fmaf(dz, wz.x, fmaf(dy, wy.x, fmaf(dx, wx.x, bse.x)));
                v.y = fmaf(dz, wz.y, fmaf(dy, wy.y, fmaf(dx, wx.y, bse.y)));
                v.z = fmaf(dz, wz.z, fmaf(dy, wy.z, fmaf(dx, wx.z, bse.z)));
                v.w = fmaf(dz, wz.w, fmaf(dy, wy.w, fmaf(dx, wx.w, bse.w)));
                if (!FIRST) {
                    v.x += g3r[r][k].x; v.y += g3r[r][k].y;
                    v.z += g3r[r][k].z; v.w += g3r[r][k].w;
                }
                m.x = fmaxf(m.x, v.x); m.y = fmaxf(m.y, v.y);
                m.z = fmaxf(m.z, v.z); m.w = fmaxf(m.w, v.w);
            }
            ushort4 mh, ml;
            mh.x = f2b(m.x); ml.x = f2b(m.x - b2f(mh.x));
            mh.y = f2b(m.y); ml.y = f2b(m.y - b2f(mh.y));
            mh.z = f2b(m.z); ml.z = f2b(m.z - b2f(mh.z));
            mh.w = f2b(m.w); ml.w = f2b(m.w - b2f(mh.w));
            *(ushort4*)&s3h[(row0 + p) * 256 + c4 * 4] = mh;
            *(ushort4*)&s3l[(row0 + p) * 256 + c4 * 4] = ml;
            if (do_head) {
                *(ushort4*)(s3H + p * 264 + c4 * 4) = mh;
                *(ushort4*)(s3L + p * 264 + c4 * 4) = ml;
            }
        }
    }

    // P6: head — h = relu(s3 @ Wm + bm) on MFMA (A from LDS bf16), motion MLP
    if (do_head) {
        __syncthreads();
        if (wv < 4) {
            int col = wv * 16 + fm;
            float bz = bm[col];
            f4_t acc = {bz, bz, bz, bz};
#pragma unroll
            for (int k0 = 0; k0 < 256; k0 += 32) {
                bf8_t ah = *(const bf8_t*)(s3H + fm * 264 + k0 + quad * 8);
                bf8_t al = *(const bf8_t*)(s3L + fm * 264 + k0 + quad * 8);
                bf8_t bh = *(const bf8_t*)(wmh + col * 256 + k0 + quad * 8);
                bf8_t bl = *(const bf8_t*)(wml + col * 256 + k0 + quad * 8);
                acc = __builtin_amdgcn_mfma_f32_16x16x32_bf16(ah, bh, acc, 0, 0, 0);
                acc = __builtin_amdgcn_mfma_f32_16x16x32_bf16(ah, bl, acc, 0, 0, 0);
                acc = __builtin_amdgcn_mfma_f32_16x16x32_bf16(al, bh, acc, 0, 0, 0);
            }
#pragma unroll
            for (int r = 0; r < 4; ++r)
                hsp[(quad * 4 + r) * 64 + col] = fmaxf(acc[r], 0.f);
        }
        __syncthreads();
        if (tid < PB * 3) {
            int p = tid / 3, d = tid % 3;
            float m = bl[d];
#pragma unroll 4
            for (int c = 0; c < 64; ++c)
                m = fmaf(hsp[p * 64 + c], Wl[c * 3 + d], m);
            const float* qp = xq + (long)b * xq_bs + (n0 + p) * 3;
            xnext[(long)b * xn_bs + (n0 + p) * 3 + d] = qp[d] + m;
        }
    }
}

// ---------------------------------------------------------------------------
// Tiled MFMA GEMM tile (unchanged from round 9/10 — verified).
// ---------------------------------------------------------------------------
template<int N>
__device__ __forceinline__ void gemmTile(
        const ushort* __restrict__ Ah, const ushort* __restrict__ Al,
        const ushort* __restrict__ Bh, const ushort* __restrict__ Bl,
        float* __restrict__ G, int rb, int cb, int tid, ushort* lds) {
    const int row0 = rb * 128, c0 = cb * 64;
    ushort* ah = lds;
    ushort* al = lds + 128 * 40;
    ushort* bh = lds + 256 * 40;
    ushort* bl = lds + 320 * 40;
    const int wv = tid >> 6, lane = tid & 63;
    const int m = lane & 15, quad = lane >> 4;
    const int wm0 = wv * 32;
    const int lr = tid >> 2, ls = (tid & 3) * 8;

    f4_t acc[2][4];
#pragma unroll
    for (int rt = 0; rt < 2; ++rt)
#pragma unroll
        for (int ct = 0; ct < 4; ++ct) acc[rt][ct] = (f4_t){0.f, 0.f, 0.f, 0.f};

    bf8_t pah0, pah1, pal0, pal1, pbh, pbl;
    pah0 = *(const bf8_t*)(Ah + (long)(row0 + lr) * N + ls);
    pah1 = *(const bf8_t*)(Ah + (long)(row0 + 64 + lr) * N + ls);
    pal0 = *(const bf8_t*)(Al + (long)(row0 + lr) * N + ls);
    pal1 = *(const bf8_t*)(Al + (long)(row0 + 64 + lr) * N + ls);
    pbh  = *(const bf8_t*)(Bh + (long)(c0 + lr) * N + ls);
    pbl  = *(const bf8_t*)(Bl + (long)(c0 + lr) * N + ls);

    for (int k0 = 0; k0 < N; k0 += 32) {
        if (k0) __syncthreads();
        *(bf8_t*)(ah + lr * 40 + ls) = pah0;
        *(bf8_t*)(ah + (64 + lr) * 40 + ls) = pah1;
        *(bf8_t*)(al + lr * 40 + ls) = pal0;
        *(bf8_t*)(al + (64 + lr) * 40 + ls) = pal1;
        *(bf8_t*)(bh + lr * 40 + ls) = pbh;
        *(bf8_t*)(bl + lr * 40 + ls) = pbl;
        __syncthreads();
        if (k0 + 32 < N) {
            int kn = k0 + 32;
            pah0 = *(const bf8_t*)(Ah + (long)(row0 + lr) * N + kn + ls);
            pah1 = *(const bf8_t*)(Ah + (long)(row0 + 64 + lr) * N + kn + ls);
            pal0 = *(const bf8_t*)(Al + (long)(row0 + lr) * N + kn + ls);
            pal1 = *(const bf8_t*)(Al + (long)(row0 + 64 + lr) * N + kn + ls);
            pbh  = *(const bf8_t*)(Bh + (long)(c0 + lr) * N + kn + ls);
            pbl  = *(const bf8_t*)(Bl + (long)(c0 + lr) * N + kn + ls);
        }
        bf8_t a0h = *(const bf8_t*)(ah + (wm0 + m) * 40 + quad * 8);
        bf8_t a0l = *(const bf8_t*)(al + (wm0 + m) * 40 + quad * 8);
        bf8_t a1h = *(const bf8_t*)(ah + (wm0 + 16 + m) * 40 + quad * 8);
        bf8_t a1l = *(const bf8_t*)(al + (wm0 + 16 + m) * 40 + quad * 8);
#pragma unroll
        for (int ct = 0; ct < 4; ++ct) {
            bf8_t bth = *(const bf8_t*)(bh + (ct * 16 + m) * 40 + quad * 8);
            bf8_t btl = *(const bf8_t*)(bl + (ct * 16 + m) * 40 + quad * 8);
            acc[0][ct] = __builtin_amdgcn_mfma_f32_16x16x32_bf16(a0h, bth, acc[0][ct], 0, 0, 0);
            acc[0][ct] = __builtin_amdgcn_mfma_f32_16x16x32_bf16(a0h, btl, acc[0][ct], 0, 0, 0);
            acc[0][ct] = __builtin_amdgcn_mfma_f32_16x16x32_bf16(a0l, bth, acc[0][ct], 0, 0, 0);
            acc[1][ct] = __builtin_amdgcn_mfma_f32_16x16x32_bf16(a1h, bth, acc[1][ct], 0, 0, 0);
            acc[1][ct] = __builtin_amdgcn_mfma_f32_16x16x32_bf16(a1h, btl, acc[1][ct], 0, 0, 0);
            acc[1][ct] = __builtin_amdgcn_mfma_f32_16x16x32_bf16(a1l, bth, acc[1][ct], 0, 0, 0);
        }
    }
#pragma unroll
    for (int rt = 0; rt < 2; ++rt)
#pragma unroll
        for (int ct = 0; ct < 4; ++ct) {
            int col = c0 + ct * 16 + m;
#pragma unroll
            for (int r = 0; r < 4; ++r)
                G[(long)(row0 + wm0 + rt * 16 + quad * 4 + r) * N + col] = acc[rt][ct][r];
        }
}

// ---------------------------------------------------------------------------
// Fused kernel B: G-GEMMs (blocks 0..447, XCD-swizzled) + next step's KNN
// (blocks 448..703) — both depend only on the preceding cells launch.
// ---------------------------------------------------------------------------
__global__ __launch_bounds__(256) void gemmG_knn_kernel(
        const ushort* __restrict__ s1h, const ushort* __restrict__ s1l,
        const ushort* __restrict__ s2h, const ushort* __restrict__ s2l,
        const ushort* __restrict__ s3h, const ushort* __restrict__ s3l,
        const ushort* __restrict__ w1h, const ushort* __restrict__ w1l,
        const ushort* __restrict__ w2h, const ushort* __restrict__ w2l,
        const ushort* __restrict__ w3h, const ushort* __restrict__ w3l,
        float* __restrict__ G1, float* __restrict__ G2,
        float* __restrict__ G3,
        const float* __restrict__ kxq, int kxq_bs,
        const float* __restrict__ kxs, int kxs_bs,
        int* __restrict__ ki1, int* __restrict__ ki2, int* __restrict__ ki3,
        float r2a, float r2b, float r2c) {
    __shared__ __attribute__((aligned(16))) char smem[30720];
    int bx = blockIdx.x, tid = threadIdx.x;
    if (bx < 256) {
        int xcd = bx & 7, rem = bx >> 3;
        int rb = xcd * 8 + (rem & 7), cb = rem >> 3;
        gemmTile<256>(s3h, s3l, w3h, w3l, G3, rb, cb, tid, (ushort*)smem);
    } else if (bx < 384) {
        int u = bx - 256; int xcd = u & 7, rem = u >> 3;
        int rb = xcd * 8 + (rem & 7), cb = rem >> 3;
        gemmTile<128>(s2h, s2l, w2h, w2l, G2, rb, cb, tid, (ushort*)smem);
    } else if (bx < 448) {
        int u = bx - 384; int xcd = u & 7, j = u >> 3;
        gemmTile<64>(s1h, s1l, w1h, w1l, G1, xcd * 8 + j, 0, tid, (ushort*)smem);
    } else {
        int u = bx - 448;
        knn_core(kxq, kxq_bs, kxs, kxs_bs, ki1, ki2, ki3,
                 r2a, r2b, r2c, u & 15, u >> 4, tid, smem);
    }
}

extern "C" void kernel_launch(void* const* d_in, const int* in_sizes, int n_in,
                              void* d_out, int out_size, void* d_ws, size_t ws_size,
                              hipStream_t stream) {
    const float* frames = (const float*)d_in[0];
    const float* W1 = (const float*)d_in[1]; const float* b1 = (const float*)d_in[2];
    const float* W2 = (const float*)d_in[3]; const float* b2 = (const float*)d_in[4];
    const float* W3 = (const float*)d_in[5]; const float* b3 = (const float*)d_in[6];
    const float* Wm = (const float*)d_in[7]; const float* bm = (const float*)d_in[8];
    const float* Wl = (const float*)d_in[9]; const float* bl = (const float*)d_in[10];
    float* out = (float*)d_out;

    const long M = (long)BB * NN;    // 8192
    float* ws = (float*)d_ws;
    float* G1b = ws; ws += M * 64;
    float* G2b = ws; ws += M * 128;
    float* G3b = ws; ws += M * 256;
    ushort* us = (ushort*)ws;
    ushort* s1h = us; us += M * 64;   ushort* s1l = us; us += M * 64;
    ushort* s2h = us; us += M * 128;  ushort* s2l = us; us += M * 128;
    ushort* s3h = us; us += M * 256;  ushort* s3l = us; us += M * 256;
    ushort* w1h = us; us += 4096;     ushort* w1l = us; us += 4096;
    ushort* w2h = us; us += 16384;    ushort* w2l = us; us += 16384;
    ushort* w3h = us; us += 65536;    ushort* w3l = us; us += 65536;
    ushort* w2fh = us; us += 8192;    ushort* w2fl = us; us += 8192;
    ushort* w3fh = us; us += 32768;   ushort* w3fl = us; us += 32768;
    ushort* wmh = us; us += 16384;    ushort* wml = us; us += 16384;
    const long BNK = M * KNN;
    int* ip = (int*)us;
    int* idx1w = ip; ip += 7 * BNK;
    int* idx2w = ip; ip += 7 * BNK;
    int* idx3w = ip; ip += 7 * BNK;

    double ra = 4.0 + 1e-6, rb = 8.0 + 1e-6, rc = 12.0 + 1e-6;
    float r2a = (float)(ra * ra), r2b = (float)(rb * rb), r2c = (float)(rc * rc);

    const int FB = SEQ * NN * 3;
    const int OB = 6 * NN * 3;

    convW_kernel<<<560, 256, 0, stream>>>(W1, W2, W3, Wm,
                                          w1h, w1l, w2h, w2l, w3h, w3l,
                                          w2fh, w2fl, w3fh, w3fl, wmh, wml);
    knn_kernel<<<dim3(NN / QB, BB, 7), 256, 0, stream>>>(
        frames, FB, nullptr, 0, idx1w, idx2w, idx3w, r2a, r2b, r2c, 1);

    for (int t = 0; t < SEQ; ++t) {
        const float* xq; int xq_bs;
        const float* xs; int xs_bs;
        if (t < 6)       { xq = frames + (long)t * NN * 3;        xq_bs = FB; }
        else if (t == 6) { xq = frames + 5L * NN * 3;             xq_bs = FB; }
        else             { xq = out + (long)(t - 7) * NN * 3;     xq_bs = OB; }
        if (t == 0)      { xs = xq;                               xs_bs = xq_bs; }
        else if (t <= 6) { xs = frames + (long)(t - 1) * NN * 3;  xs_bs = FB; }
        else if (t == 7) { xs = frames + 5L * NN * 3;             xs_bs = FB; }
        else             { xs = out + (long)(t - 8) * NN * 3;     xs_bs = OB; }

        int slot = (t <= 6) ? t : 0;   // t>=7 uses slot 0 (written by fused knn)
        int* i1 = idx1w + slot * BNK;
        int* i2 = idx2w + slot * BNK;
        int* i3 = idx3w + slot * BNK;

        int do_head = (t >= 6);
        float* xnext = do_head ? out + (long)(t - 6) * NN * 3 : nullptr;

        if (t == 0)
            cells_kernel<true><<<BB * NN / PB, 512, 0, stream>>>(
                xq, xq_bs, xs, xs_bs, i1, i2, i3,
                G1b, G2b, G3b, s1h, s1l, s2h, s2l, s3h, s3l,
                W1, b1, W2, b2, W3, b3,
                w2fh, w2fl, w3fh, w3fl, wmh, wml, bm,
                Wl, bl, xnext, OB, do_head);
        else
            cells_kernel<false><<<BB * NN / PB, 512, 0, stream>>>(
                xq, xq_bs, xs, xs_bs, i1, i2, i3,
                G1b, G2b, G3b, s1h, s1l, s2h, s2l, s3h, s3l,
                W1, b1, W2, b2, W3, b3,
                w2fh, w2fl, w3fh, w3fl, wmh, wml, bm,
                Wl, bl, xnext, OB, do_head);

        // G for step t+1 (+ knn for step t+1 when t+1 >= 7) — both depend
        // only on cells_t, so they share one dispatch and run concurrently.
        if (t < SEQ - 1) {
            bool dk = (t + 1 >= 7);
            const float* kxq = frames; int kxq_bs = FB;
            const float* kxs = frames; int kxs_bs = FB;
            if (dk) {
                kxq = out + (long)(t + 1 - 7) * NN * 3; kxq_bs = OB;
                if (t + 1 == 7) { kxs = frames + 5L * NN * 3; kxs_bs = FB; }
                else            { kxs = out + (long)(t + 1 - 8) * NN * 3; kxs_bs = OB; }
            }
            gemmG_knn_kernel<<<448 + (dk ? 256 : 0), 256, 0, stream>>>(
                s1h, s1l, s2h, s2l, s3h, s3l,
                w1h, w1l, w2h, w2l, w3h, w3l,
                G1b, G2b, G3b,
                kxq, kxq_bs, kxs, kxs_bs,
                idx1w, idx2w, idx3w, r2a, r2b, r2c);
        }
    }
}

// Round 12
// 592.421 us; speedup vs baseline: 1.0033x; 1.0033x over previous
//
#include <hip/hip_runtime.h>
#include <math.h>

#define BB 16
#define NN 512
#define KNN 8
#define SEQ 12
#define TQ 8            // knn: threads per query
#define QB 32           // knn: queries per block (TQ*QB = 256 threads)
#define PB 16           // cells: points per block

typedef __attribute__((ext_vector_type(8))) short bf8_t;   // 8 bf16 (4 VGPRs)
typedef __attribute__((ext_vector_type(4))) float f4_t;    // MFMA acc

__device__ __forceinline__ ushort f2b(float x) {           // fp32 -> bf16 RNE
    uint u = __float_as_uint(x);
    return (ushort)((u + 0x7fffu + ((u >> 16) & 1u)) >> 16);
}
__device__ __forceinline__ float b2f(ushort h) {
    return __uint_as_float((uint)h << 16);
}
// 8 consecutive fp32 -> hi/lo bf16 fragments (used only in head phase)
__device__ __forceinline__ void cvt8(const float* __restrict__ p,
                                     bf8_t& h, bf8_t& l) {
    float4 x0 = *(const float4*)p;
    float4 x1 = *(const float4*)(p + 4);
    float v[8] = {x0.x, x0.y, x0.z, x0.w, x1.x, x1.y, x1.z, x1.w};
#pragma unroll
    for (int i = 0; i < 8; ++i) {
        ushort hh = f2b(v[i]);
        h[i] = (short)hh;
        l[i] = (short)f2b(v[i] - b2f(hh));
    }
}

// ---------------------------------------------------------------------------
// KNN standalone (warmup only, warm=1 path) — unchanged, verified correct.
// ---------------------------------------------------------------------------
__global__ __launch_bounds__(256) void knn_kernel(
        const float* __restrict__ xq, int xq_bs,
        const float* __restrict__ xs, int xs_bs,
        int* __restrict__ idx1, int* __restrict__ idx2, int* __restrict__ idx3,
        float r2a, float r2b, float r2c, int warm) {
    __shared__ float s[NN * 3 + NN / 64];
    __shared__ float cd[QB][TQ][KNN + 1];
    __shared__ int   ci[QB][TQ][KNN + 1];
    int b = blockIdx.y;
    const float* xqp; const float* xsp; long iofs;
    if (warm) {
        int z = blockIdx.z;
        int qz = z < 5 ? z : 5;
        int sz = z - 1 < 0 ? 0 : z - 1;
        xqp = xq + (long)qz * NN * 3;
        xsp = xq + (long)sz * NN * 3;
        xs_bs = xq_bs;
        iofs = (long)z * BB * NN * KNN;
    } else {
        xqp = xq; xsp = xs; iofs = 0;
    }

    for (int j = threadIdx.x; j < NN; j += 256) {
        const float* p = xsp + (long)b * xs_bs + j * 3;
        int o = 3 * j + (j >> 6);
        s[o + 0] = p[0]; s[o + 1] = p[1]; s[o + 2] = p[2];
    }
    __syncthreads();

    int qi  = threadIdx.x / TQ;
    int sub = threadIdx.x % TQ;
    int n = blockIdx.x * QB + qi;
    const float* q = xqp + (long)b * xq_bs + n * 3;
    float qx = q[0], qy = q[1], qz2 = q[2];

    float bd[KNN];
    int   bi[KNN];
#pragma unroll
    for (int k = 0; k < KNN; ++k) { bd[k] = 1e30f; bi[k] = 0; }

    int j0 = sub * (NN / TQ);
    int sbase = 3 * j0 + sub;
#pragma unroll 4
    for (int jj = 0; jj < NN / TQ; ++jj) {
        float dx = s[sbase + 3 * jj + 0] - qx;
        float dy = s[sbase + 3 * jj + 1] - qy;
        float dz = s[sbase + 3 * jj + 2] - qz2;
        float d2 = fmaf(dx, dx, fmaf(dy, dy, dz * dz));
        if (d2 < bd[KNN - 1]) {
            bd[KNN - 1] = d2; bi[KNN - 1] = j0 + jj;
#pragma unroll
            for (int k = KNN - 1; k >= 1; --k) {
                if (bd[k] < bd[k - 1]) {
                    float td = bd[k]; bd[k] = bd[k - 1]; bd[k - 1] = td;
                    int   ti = bi[k]; bi[k] = bi[k - 1]; bi[k - 1] = ti;
                }
            }
        }
    }

#pragma unroll
    for (int k = 0; k < KNN; ++k) { cd[qi][sub][k] = bd[k]; ci[qi][sub][k] = bi[k]; }
    cd[qi][sub][KNN] = 1e30f; ci[qi][sub][KNN] = 0x7fffffff;
    __syncthreads();

    for (int stride = TQ / 2; stride >= 1; stride >>= 1) {
        if (sub < stride) {
            float rd[KNN]; int ri[KNN];
            int ia = 0, ib = 0;
#pragma unroll
            for (int k = 0; k < KNN; ++k) {
                float da = cd[qi][sub][ia], db = cd[qi][sub + stride][ib];
                int   ja = ci[qi][sub][ia], jb = ci[qi][sub + stride][ib];
                bool ta = (da < db) || (da == db && ja < jb);
                rd[k] = ta ? da : db; ri[k] = ta ? ja : jb;
                ia += ta ? 1 : 0; ib += ta ? 0 : 1;
            }
#pragma unroll
            for (int k = 0; k < KNN; ++k) { cd[qi][sub][k] = rd[k]; ci[qi][sub][k] = ri[k]; }
        }
        __syncthreads();
    }

    if (sub == 0) {
        long base = iofs + ((long)(b * NN + n)) * KNN;
        int i0 = ci[qi][0][0];
#pragma unroll
        for (int k = 0; k < KNN; ++k) {
            float d = cd[qi][0][k]; int j = ci[qi][0][k];
            idx1[base + k] = (d <= r2a) ? j : i0;
            idx2[base + k] = (d <= r2b) ? j : i0;
            idx3[base + k] = (d <= r2c) ? j : i0;
        }
    }
}

// knn core as device function (for the fused gemmG+knn dispatch)
__device__ void knn_core(const float* __restrict__ xq, int xq_bs,
                         const float* __restrict__ xs, int xs_bs,
                         int* __restrict__ idx1, int* __restrict__ idx2,
                         int* __restrict__ idx3,
                         float r2a, float r2b, float r2c,
                         int bx, int b, int tid, char* smem) {
    float* s  = (float*)smem;            // [NN*3 + NN/64] = 1544 f
    float* cd = s + 1544;                // [32][8][9]
    int*   ci = (int*)(cd + 2304);       // [32][8][9]

    for (int j = tid; j < NN; j += 256) {
        const float* p = xs + (long)b * xs_bs + j * 3;
        int o = 3 * j + (j >> 6);
        s[o + 0] = p[0]; s[o + 1] = p[1]; s[o + 2] = p[2];
    }
    __syncthreads();

    int qi = tid / TQ, sub = tid % TQ;
    int n = bx * QB + qi;
    const float* q = xq + (long)b * xq_bs + n * 3;
    float qx = q[0], qy = q[1], qz2 = q[2];

    float bd[KNN]; int bi[KNN];
#pragma unroll
    for (int k = 0; k < KNN; ++k) { bd[k] = 1e30f; bi[k] = 0; }

    int j0 = sub * (NN / TQ);
    int sbase = 3 * j0 + sub;
#pragma unroll 4
    for (int jj = 0; jj < NN / TQ; ++jj) {
        float dx = s[sbase + 3 * jj + 0] - qx;
        float dy = s[sbase + 3 * jj + 1] - qy;
        float dz = s[sbase + 3 * jj + 2] - qz2;
        float d2 = fmaf(dx, dx, fmaf(dy, dy, dz * dz));
        if (d2 < bd[KNN - 1]) {
            bd[KNN - 1] = d2; bi[KNN - 1] = j0 + jj;
#pragma unroll
            for (int k = KNN - 1; k >= 1; --k) {
                if (bd[k] < bd[k - 1]) {
                    float td = bd[k]; bd[k] = bd[k - 1]; bd[k - 1] = td;
                    int   ti = bi[k]; bi[k] = bi[k - 1]; bi[k - 1] = ti;
                }
            }
        }
    }

    int b9 = (qi * 8 + sub) * 9;
#pragma unroll
    for (int k = 0; k < KNN; ++k) { cd[b9 + k] = bd[k]; ci[b9 + k] = bi[k]; }
    cd[b9 + KNN] = 1e30f; ci[b9 + KNN] = 0x7fffffff;
    __syncthreads();

    for (int stride = TQ / 2; stride >= 1; stride >>= 1) {
        if (sub < stride) {
            int a9 = (qi * 8 + sub) * 9, c9 = (qi * 8 + sub + stride) * 9;
            float rd[KNN]; int ri[KNN];
            int ia = 0, ib = 0;
#pragma unroll
            for (int k = 0; k < KNN; ++k) {
                float da = cd[a9 + ia], db = cd[c9 + ib];
                int   ja = ci[a9 + ia], jb = ci[c9 + ib];
                bool ta = (da < db) || (da == db && ja < jb);
                rd[k] = ta ? da : db; ri[k] = ta ? ja : jb;
                ia += ta ? 1 : 0; ib += ta ? 0 : 1;
            }
#pragma unroll
            for (int k = 0; k < KNN; ++k) { cd[a9 + k] = rd[k]; ci[a9 + k] = ri[k]; }
        }
        __syncthreads();
    }

    if (sub == 0) {
        int a9 = (qi * 8) * 9;
        long base = ((long)(b * NN + n)) * KNN;
        int i0 = ci[a9];
#pragma unroll
        for (int k = 0; k < KNN; ++k) {
            float d = cd[a9 + k]; int j = ci[a9 + k];
            idx1[base + k] = (d <= r2a) ? j : i0;
            idx2[base + k] = (d <= r2b) ? j : i0;
            idx3[base + k] = (d <= r2c) ? j : i0;
        }
    }
}

// ---------------------------------------------------------------------------
// One-time weight conversion to transposed split-bf16.
// ---------------------------------------------------------------------------
__global__ __launch_bounds__(256) void convW_kernel(
        const float* __restrict__ W1, const float* __restrict__ W2,
        const float* __restrict__ W3, const float* __restrict__ Wm,
        ushort* __restrict__ w1h, ushort* __restrict__ w1l,
        ushort* __restrict__ w2h, ushort* __restrict__ w2l,
        ushort* __restrict__ w3h, ushort* __restrict__ w3l,
        ushort* __restrict__ w2fh, ushort* __restrict__ w2fl,
        ushort* __restrict__ w3fh, ushort* __restrict__ w3fl,
        ushort* __restrict__ wmh, ushort* __restrict__ wml) {
    int t = blockIdx.x * 256 + threadIdx.x;
    float v; ushort* ph; ushort* pl; int idx;
    if (t < 4096)        { int n = t >> 6, k = t & 63;
        v = W1[(3 + k) * 64 + n];   ph = w1h;  pl = w1l;  idx = t; }
    else if (t < 20480)  { int u = t - 4096, n = u >> 7, k = u & 127;
        v = W2[(67 + k) * 128 + n]; ph = w2h;  pl = w2l;  idx = u; }
    else if (t < 86016)  { int u = t - 20480, n = u >> 8, k = u & 255;
        v = W3[(131 + k) * 256 + n]; ph = w3h; pl = w3l;  idx = u; }
    else if (t < 94208)  { int u = t - 86016, n = u >> 6, k = u & 63;
        v = W2[(3 + k) * 128 + n];  ph = w2fh; pl = w2fl; idx = u; }
    else if (t < 126976) { int u = t - 94208, n = u >> 7, k = u & 127;
        v = W3[(3 + k) * 256 + n];  ph = w3fh; pl = w3fl; idx = u; }
    else if (t < 143360) { int u = t - 126976, n = u >> 8, k = u & 255;
        v = Wm[k * 64 + n];         ph = wmh;  pl = wml;  idx = u; }
    else return;
    ushort h = f2b(v);
    ph[idx] = h; pl[idx] = f2b(v - b2f(h));
}

// ---------------------------------------------------------------------------
// Kernel A: combines on VALU, bases on MFMA with LDS-staged split-bf16.
// COMPACT lifetime-overlay pool = 31488 B -> 4 blocks/CU (was 44544 -> 3,
// the round-11 regression). s3b overlays s1H/s1L+s2s (both dead by P4);
// head converts from fp32 s3b (cvt only 6/12 steps, 4 waves).
// ---------------------------------------------------------------------------
template<bool FIRST>
__global__ __launch_bounds__(512, 4) void cells_kernel(
        const float* __restrict__ xq, int xq_bs,
        const float* __restrict__ xs, int xs_bs,
        const int* __restrict__ i1, const int* __restrict__ i2,
        const int* __restrict__ i3,
        const float* __restrict__ G1p, const float* __restrict__ G2p,
        const float* __restrict__ G3p,
        ushort* __restrict__ s1h, ushort* __restrict__ s1l,
        ushort* __restrict__ s2h, ushort* __restrict__ s2l,
        ushort* __restrict__ s3h, ushort* __restrict__ s3l,
        const float* __restrict__ W1, const float* __restrict__ b1,
        const float* __restrict__ W2, const float* __restrict__ b2,
        const float* __restrict__ W3, const float* __restrict__ b3,
        const ushort* __restrict__ w2fh, const ushort* __restrict__ w2fl,
        const ushort* __restrict__ w3fh, const ushort* __restrict__ w3fl,
        const ushort* __restrict__ wmh, const ushort* __restrict__ wml,
        const float* __restrict__ bm,
        const float* __restrict__ Wl, const float* __restrict__ bl,
        float* __restrict__ xnext, int xn_bs, int do_head) {
    // Compact pool (31488 B), lifetimes:
    //  [0,4608)      dsp  (P0->P5; hs overlays in P6)
    //  [4608,6144)   jss  (P0 -> g3 prefetch)
    //  [6144,14848)  s2H/s2L [16][136]u  (P3->P4)
    //  [14848,19456) s1H/s1L [16][72]u   (P1->P2; s3b overlays from P4)
    //  [19456,27904) s2s fp32 [16][132]  (P2->P3; s3b overlays from P4)
    //  [14848,31488) s3b fp32 [16][260]  (P4->P5/P6)
    __shared__ __attribute__((aligned(16))) char pool[31488];
    float*  dspf = (float*)pool;
    int*    jssp = (int*)(pool + 4608);
    ushort* s2H  = (ushort*)(pool + 6144);
    ushort* s2L  = (ushort*)(pool + 10496);
    ushort* s1H  = (ushort*)(pool + 14848);
    ushort* s1L  = (ushort*)(pool + 17152);
    float*  s2sp = (float*)(pool + 19456);
    float*  s3bp = (float*)(pool + 14848);     // overlays s1H/s1L + s2s
    float*  hsp  = (float*)pool;               // [16][64], overlays dsp (P6)

    const int tid = threadIdx.x;
    const int blk = blockIdx.x;          // 0..511
    const int xcd = blk & 7, slot = blk >> 3;
    const int b   = xcd * 2 + (slot >> 5);     // batch <-> XCD affinity
    const int n0  = (slot & 31) << 4;
    const long row0 = (long)b * NN + n0;
    const long bN = (long)b * NN;
    const int wv = tid >> 6, lane = tid & 63;
    const int fm = lane & 15, quad = lane >> 4;

    // P0: neighbor indices + displacements
    for (int t = tid; t < 3 * PB * KNN; t += 512) {
        int r = t >> 7, rem = t & 127, p = rem >> 3, k = rem & 7;
        const int* ix = (r == 0) ? i1 : ((r == 1) ? i2 : i3);
        int j = ix[(row0 + p) * KNN + k];
        jssp[t] = j;
        const float* sp = xs + (long)b * xs_bs + j * 3;
        const float* qp = xq + (long)b * xq_bs + (n0 + p) * 3;
        dspf[t * 3 + 0] = sp[0] - qp[0];
        dspf[t * 3 + 1] = sp[1] - qp[1];
        dspf[t * 3 + 2] = sp[2] - qp[2];
    }
    __syncthreads();

    // P1: cell1 combine -> split-bf16 to global + LDS
    {
        int co = tid & 63, q = tid >> 6;
        float g1r[2][KNN];
        if (!FIRST) {
#pragma unroll
            for (int r = 0; r < 2; ++r)
#pragma unroll
                for (int k = 0; k < KNN; ++k)
                    g1r[r][k] = G1p[(bN + jssp[(2 * q + r) * 8 + k]) * 64 + co];
        }
        float wx = W1[co], wy = W1[64 + co], wz = W1[128 + co];
        float bz = b1[co];
#pragma unroll
        for (int r = 0; r < 2; ++r) {
            int p = 2 * q + r;
            float acc = -1e30f;
#pragma unroll
            for (int k = 0; k < KNN; ++k) {
                int di = (p * 8 + k) * 3;
                float v = fmaf(dspf[di + 0], wx, bz);
                v = fmaf(dspf[di + 1], wy, v);
                v = fmaf(dspf[di + 2], wz, v);
                if (!FIRST) v += g1r[r][k];
                acc = fmaxf(acc, v);
            }
            ushort h = f2b(acc);
            ushort l = f2b(acc - b2f(h));
            s1h[(row0 + p) * 64 + co] = h;
            s1l[(row0 + p) * 64 + co] = l;
            s1H[p * 72 + co] = h;
            s1L[p * 72 + co] = l;
        }
    }
    __syncthreads();

    // G2 gathers prefetched (consumed in P3, hidden behind P2 MFMA)
    float4 g2r[KNN];
    {
        int c4 = tid & 31, g = tid >> 5;
        if (!FIRST) {
#pragma unroll
            for (int k = 0; k < KNN; ++k)
                g2r[k] = ((const float4*)G2p)[(bN + jssp[(16 + g) * 8 + k]) * 32 + c4];
        }
    }

    // P2: base2 = s1 @ W2f + b2 on MFMA (A-frags from LDS bf16, no cvt)
    {
        int col = wv * 16 + fm;
        float bz = b2[col];
        f4_t acc = {bz, bz, bz, bz};
#pragma unroll
        for (int k0 = 0; k0 < 64; k0 += 32) {
            bf8_t ah = *(const bf8_t*)(s1H + fm * 72 + k0 + quad * 8);
            bf8_t al = *(const bf8_t*)(s1L + fm * 72 + k0 + quad * 8);
            bf8_t bh = *(const bf8_t*)(w2fh + col * 64 + k0 + quad * 8);
            bf8_t bl = *(const bf8_t*)(w2fl + col * 64 + k0 + quad * 8);
            acc = __builtin_amdgcn_mfma_f32_16x16x32_bf16(ah, bh, acc, 0, 0, 0);
            acc = __builtin_amdgcn_mfma_f32_16x16x32_bf16(ah, bl, acc, 0, 0, 0);
            acc = __builtin_amdgcn_mfma_f32_16x16x32_bf16(al, bh, acc, 0, 0, 0);
        }
#pragma unroll
        for (int r = 0; r < 4; ++r) s2sp[(quad * 4 + r) * 132 + col] = acc[r];
    }
    __syncthreads();

    // P3: combine2 -> split-bf16 to global + LDS (split computed once here)
    {
        int c4 = tid & 31, g = tid >> 5;
        float4 bse = *(float4*)&s2sp[g * 132 + c4 * 4];
        float4 wx = ((const float4*)W2)[c4];
        float4 wy = ((const float4*)(W2 + 128))[c4];
        float4 wz = ((const float4*)(W2 + 256))[c4];
        float4 m = make_float4(-1e30f, -1e30f, -1e30f, -1e30f);
#pragma unroll
        for (int k = 0; k < KNN; ++k) {
            int di = ((16 + g) * 8 + k) * 3;
            float dx = dspf[di + 0], dy = dspf[di + 1], dz = dspf[di + 2];
            float4 v;
            v.x = fmaf(dz, wz.x, fmaf(dy, wy.x, fmaf(dx, wx.x, bse.x)));
            v.y = fmaf(dz, wz.y, fmaf(dy, wy.y, fmaf(dx, wx.y, bse.y)));
            v.z = fmaf(dz, wz.z, fmaf(dy, wy.z, fmaf(dx, wx.z, bse.z)));
            v.w = fmaf(dz, wz.w, fmaf(dy, wy.w, fmaf(dx, wx.w, bse.w)));
            if (!FIRST) {
                v.x += g2r[k].x; v.y += g2r[k].y;
                v.z += g2r[k].z; v.w += g2r[k].w;
            }
            m.x = fmaxf(m.x, v.x); m.y = fmaxf(m.y, v.y);
            m.z = fmaxf(m.z, v.z); m.w = fmaxf(m.w, v.w);
        }
        ushort4 mh, ml;
        mh.x = f2b(m.x); ml.x = f2b(m.x - b2f(mh.x));
        mh.y = f2b(m.y); ml.y = f2b(m.y - b2f(mh.y));
        mh.z = f2b(m.z); ml.z = f2b(m.z - b2f(mh.z));
        mh.w = f2b(m.w); ml.w = f2b(m.w - b2f(mh.w));
        *(ushort4*)&s2h[(row0 + g) * 128 + c4 * 4] = mh;
        *(ushort4*)&s2l[(row0 + g) * 128 + c4 * 4] = ml;
        *(ushort4*)(s2H + g * 136 + c4 * 4) = mh;
        *(ushort4*)(s2L + g * 136 + c4 * 4) = ml;
    }
    __syncthreads();

    // G3 gathers prefetched (consumed in P5, hidden behind P4 MFMA)
    float4 g3r[2][KNN];
    {
        int c4 = tid & 63, g = tid >> 6;
        if (!FIRST) {
#pragma unroll
            for (int r = 0; r < 2; ++r)
#pragma unroll
                for (int k = 0; k < KNN; ++k)
                    g3r[r][k] = ((const float4*)G3p)[(bN + jssp[(32 + 2 * g + r) * 8 + k]) * 64 + c4];
        }
    }

    // P4: base3 = s2 @ W3f + b3 on MFMA (A from LDS bf16) -> s3b
    // (s3b overlays s1H/s1L+s2s — both dead; barrier above protects s2s)
    {
        int col0 = wv * 16 + fm, col1 = (wv + 8) * 16 + fm;
        float bz0 = b3[col0], bz1 = b3[col1];
        f4_t a0 = {bz0, bz0, bz0, bz0};
        f4_t a1 = {bz1, bz1, bz1, bz1};
#pragma unroll
        for (int k0 = 0; k0 < 128; k0 += 32) {
            bf8_t ah = *(const bf8_t*)(s2H + fm * 136 + k0 + quad * 8);
            bf8_t al = *(const bf8_t*)(s2L + fm * 136 + k0 + quad * 8);
            bf8_t b0h = *(const bf8_t*)(w3fh + col0 * 128 + k0 + quad * 8);
            bf8_t b0l = *(const bf8_t*)(w3fl + col0 * 128 + k0 + quad * 8);
            bf8_t b1h = *(const bf8_t*)(w3fh + col1 * 128 + k0 + quad * 8);
            bf8_t b1l = *(const bf8_t*)(w3fl + col1 * 128 + k0 + quad * 8);
            a0 = __builtin_amdgcn_mfma_f32_16x16x32_bf16(ah, b0h, a0, 0, 0, 0);
            a0 = __builtin_amdgcn_mfma_f32_16x16x32_bf16(ah, b0l, a0, 0, 0, 0);
            a0 = __builtin_amdgcn_mfma_f32_16x16x32_bf16(al, b0h, a0, 0, 0, 0);
            a1 = __builtin_amdgcn_mfma_f32_16x16x32_bf16(ah, b1h, a1, 0, 0, 0);
            a1 = __builtin_amdgcn_mfma_f32_16x16x32_bf16(ah, b1l, a1, 0, 0, 0);
            a1 = __builtin_amdgcn_mfma_f32_16x16x32_bf16(al, b1h, a1, 0, 0, 0);
        }
#pragma unroll
        for (int r = 0; r < 4; ++r) {
            s3bp[(quad * 4 + r) * 260 + col0] = a0[r];
            s3bp[(quad * 4 + r) * 260 + col1] = a1[r];
        }
    }
    __syncthreads();

    // P5: combine3 -> split-bf16 to global; combined fp32 back into s3b
    {
        int c4 = tid & 63, g = tid >> 6;
        float4 wx = ((const float4*)W3)[c4];
        float4 wy = ((const float4*)(W3 + 256))[c4];
        float4 wz = ((const float4*)(W3 + 512))[c4];
#pragma unroll
        for (int r = 0; r < 2; ++r) {
            int p = 2 * g + r;
            float4 bse = *(float4*)&s3bp[p * 260 + c4 * 4];
            float4 m = make_float4(-1e30f, -1e30f, -1e30f, -1e30f);
#pragma unroll
            for (int k = 0; k < KNN; ++k) {
                int di = ((32 + p) * 8 + k) * 3;
                float dx = dspf[di + 0], dy = dspf[di + 1], dz = dspf[di + 2];
                float4 v;
                v.x = fmaf(dz, wz.x, fmaf(dy, wy.x, fmaf(dx, wx.x, bse.x)));
                v.y = fmaf(dz, wz.y, fmaf(dy, wy.y, fmaf(dx, wx.y, bse.y)));
                v.z = fmaf(dz, wz.z, fmaf(dy, wy.z, fmaf(dx, wx.z, bse.z)));
                v.w = fmaf(dz, wz.w, fmaf(dy, wy.w, fmaf(dx, wx.w, bse.w)));
                if (!FIRST) {
                    v.x += g3r[r][k].x; v.y += g3r[r][k].y;
                    v.z += g3r[r][k].z; v.w += g3r[r][k].w;
                }
                m.x = fmaxf(m.x, v.x); m.y = fmaxf(m.y, v.y);
                m.z = fmaxf(m.z, v.z); m.w = fmaxf(m.w, v.w);
            }
            *(float4*)&s3bp[p * 260 + c4 * 4] = m;   // in place (thread-owned)
            ushort4 mh, ml;
            mh.x = f2b(m.x); ml.x = f2b(m.x - b2f(mh.x));
            mh.y = f2b(m.y); ml.y = f2b(m.y - b2f(mh.y));
            mh.z = f2b(m.z); ml.z = f2b(m.z - b2f(mh.z));
            mh.w = f2b(m.w); ml.w = f2b(m.w - b2f(mh.w));
            *(ushort4*)&s3h[(row0 + p) * 256 + c4 * 4] = mh;
            *(ushort4*)&s3l[(row0 + p) * 256 + c4 * 4] = ml;
        }
    }

    // P6: head — h = relu(s3 @ Wm + bm) on MFMA (cvt from fp32 s3b), motion
    if (do_head) {
        __syncthreads();
        if (wv < 4) {
            int col = wv * 16 + fm;
            float bz = bm[col];
            f4_t acc = {bz, bz, bz, bz};
#pragma unroll
            for (int k0 = 0; k0 < 256; k0 += 32) {
                bf8_t ah, al; cvt8(&s3bp[fm * 260 + k0 + quad * 8], ah, al);
                bf8_t bh = *(const bf8_t*)(wmh + col * 256 + k0 + quad * 8);
                bf8_t bl = *(const bf8_t*)(wml + col * 256 + k0 + quad * 8);
                acc = __builtin_amdgcn_mfma_f32_16x16x32_bf16(ah, bh, acc, 0, 0, 0);
                acc = __builtin_amdgcn_mfma_f32_16x16x32_bf16(ah, bl, acc, 0, 0, 0);
                acc = __builtin_amdgcn_mfma_f32_16x16x32_bf16(al, bh, acc, 0, 0, 0);
            }
#pragma unroll
            for (int r = 0; r < 4; ++r)
                hsp[(quad * 4 + r) * 64 + col] = fmaxf(acc[r], 0.f);
        }
        __syncthreads();
        if (tid < PB * 3) {
            int p = tid / 3, d = tid % 3;
            float m = bl[d];
#pragma unroll 4
            for (int c = 0; c < 64; ++c)
                m = fmaf(hsp[p * 64 + c], Wl[c * 3 + d], m);
            const float* qp = xq + (long)b * xq_bs + (n0 + p) * 3;
            xnext[(long)b * xn_bs + (n0 + p) * 3 + d] = qp[d] + m;
        }
    }
}

// ---------------------------------------------------------------------------
// Tiled MFMA GEMM tile (unchanged — verified).
// ---------------------------------------------------------------------------
template<int N>
__device__ __forceinline__ void gemmTile(
        const ushort* __restrict__ Ah, const ushort* __restrict__ Al,
        const ushort* __restrict__ Bh, const ushort* __restrict__ Bl,
        float* __restrict__ G, int rb, int cb, int tid, ushort* lds) {
    const int row0 = rb * 128, c0 = cb * 64;
    ushort* ah = lds;
    ushort* al = lds + 128 * 40;
    ushort* bh = lds + 256 * 40;
    ushort* bl = lds + 320 * 40;
    const int wv = tid >> 6, lane = tid & 63;
    const int m = lane & 15, quad = lane >> 4;
    const int wm0 = wv * 32;
    const int lr = tid >> 2, ls = (tid & 3) * 8;

    f4_t acc[2][4];
#pragma unroll
    for (int rt = 0; rt < 2; ++rt)
#pragma unroll
        for (int ct = 0; ct < 4; ++ct) acc[rt][ct] = (f4_t){0.f, 0.f, 0.f, 0.f};

    bf8_t pah0, pah1, pal0, pal1, pbh, pbl;
    pah0 = *(const bf8_t*)(Ah + (long)(row0 + lr) * N + ls);
    pah1 = *(const bf8_t*)(Ah + (long)(row0 + 64 + lr) * N + ls);
    pal0 = *(const bf8_t*)(Al + (long)(row0 + lr) * N + ls);
    pal1 = *(const bf8_t*)(Al + (long)(row0 + 64 + lr) * N + ls);
    pbh  = *(const bf8_t*)(Bh + (long)(c0 + lr) * N + ls);
    pbl  = *(const bf8_t*)(Bl + (long)(c0 + lr) * N + ls);

    for (int k0 = 0; k0 < N; k0 += 32) {
        if (k0) __syncthreads();
        *(bf8_t*)(ah + lr * 40 + ls) = pah0;
        *(bf8_t*)(ah + (64 + lr) * 40 + ls) = pah1;
        *(bf8_t*)(al + lr * 40 + ls) = pal0;
        *(bf8_t*)(al + (64 + lr) * 40 + ls) = pal1;
        *(bf8_t*)(bh + lr * 40 + ls) = pbh;
        *(bf8_t*)(bl + lr * 40 + ls) = pbl;
        __syncthreads();
        if (k0 + 32 < N) {
            int kn = k0 + 32;
            pah0 = *(const bf8_t*)(Ah + (long)(row0 + lr) * N + kn + ls);
            pah1 = *(const bf8_t*)(Ah + (long)(row0 + 64 + lr) * N + kn + ls);
            pal0 = *(const bf8_t*)(Al + (long)(row0 + lr) * N + kn + ls);
            pal1 = *(const bf8_t*)(Al + (long)(row0 + 64 + lr) * N + kn + ls);
            pbh  = *(const bf8_t*)(Bh + (long)(c0 + lr) * N + kn + ls);
            pbl  = *(const bf8_t*)(Bl + (long)(c0 + lr) * N + kn + ls);
        }
        bf8_t a0h = *(const bf8_t*)(ah + (wm0 + m) * 40 + quad * 8);
        bf8_t a0l = *(const bf8_t*)(al + (wm0 + m) * 40 + quad * 8);
        bf8_t a1h = *(const bf8_t*)(ah + (wm0 + 16 + m) * 40 + quad * 8);
        bf8_t a1l = *(const bf8_t*)(al + (wm0 + 16 + m) * 40 + quad * 8);
#pragma unroll
        for (int ct = 0; ct < 4; ++ct) {
            bf8_t bth = *(const bf8_t*)(bh + (ct * 16 + m) * 40 + quad * 8);
            bf8_t btl = *(const bf8_t*)(bl + (ct * 16 + m) * 40 + quad * 8);
            acc[0][ct] = __builtin_amdgcn_mfma_f32_16x16x32_bf16(a0h, bth, acc[0][ct], 0, 0, 0);
            acc[0][ct] = __builtin_amdgcn_mfma_f32_16x16x32_bf16(a0h, btl, acc[0][ct], 0, 0, 0);
            acc[0][ct] = __builtin_amdgcn_mfma_f32_16x16x32_bf16(a0l, bth, acc[0][ct], 0, 0, 0);
            acc[1][ct] = __builtin_amdgcn_mfma_f32_16x16x32_bf16(a1h, bth, acc[1][ct], 0, 0, 0);
            acc[1][ct] = __builtin_amdgcn_mfma_f32_16x16x32_bf16(a1h, btl, acc[1][ct], 0, 0, 0);
            acc[1][ct] = __builtin_amdgcn_mfma_f32_16x16x32_bf16(a1l, bth, acc[1][ct], 0, 0, 0);
        }
    }
#pragma unroll
    for (int rt = 0; rt < 2; ++rt)
#pragma unroll
        for (int ct = 0; ct < 4; ++ct) {
            int col = c0 + ct * 16 + m;
#pragma unroll
            for (int r = 0; r < 4; ++r)
                G[(long)(row0 + wm0 + rt * 16 + quad * 4 + r) * N + col] = acc[rt][ct][r];
        }
}

// ---------------------------------------------------------------------------
// Fused kernel B: G-GEMMs (blocks 0..447, XCD-swizzled) + next step's KNN
// (blocks 448..703) — both depend only on the preceding cells launch.
// ---------------------------------------------------------------------------
__global__ __launch_bounds__(256) void gemmG_knn_kernel(
        const ushort* __restrict__ s1h, const ushort* __restrict__ s1l,
        const ushort* __restrict__ s2h, const ushort* __restrict__ s2l,
        const ushort* __restrict__ s3h, const ushort* __restrict__ s3l,
        const ushort* __restrict__ w1h, const ushort* __restrict__ w1l,
        const ushort* __restrict__ w2h, const ushort* __restrict__ w2l,
        const ushort* __restrict__ w3h, const ushort* __restrict__ w3l,
        float* __restrict__ G1, float* __restrict__ G2,
        float* __restrict__ G3,
        const float* __restrict__ kxq, int kxq_bs,
        const float* __restrict__ kxs, int kxs_bs,
        int* __restrict__ ki1, int* __restrict__ ki2, int* __restrict__ ki3,
        float r2a, float r2b, float r2c) {
    __shared__ __attribute__((aligned(16))) char smem[30720];
    int bx = blockIdx.x, tid = threadIdx.x;
    if (bx < 256) {
        int xcd = bx & 7, rem = bx >> 3;
        int rb = xcd * 8 + (rem & 7), cb = rem >> 3;
        gemmTile<256>(s3h, s3l, w3h, w3l, G3, rb, cb, tid, (ushort*)smem);
    } else if (bx < 384) {
        int u = bx - 256; int xcd = u & 7, rem = u >> 3;
        int rb = xcd * 8 + (rem & 7), cb = rem >> 3;
        gemmTile<128>(s2h, s2l, w2h, w2l, G2, rb, cb, tid, (ushort*)smem);
    } else if (bx < 448) {
        int u = bx - 384; int xcd = u & 7, j = u >> 3;
        gemmTile<64>(s1h, s1l, w1h, w1l, G1, xcd * 8 + j, 0, tid, (ushort*)smem);
    } else {
        int u = bx - 448;
        knn_core(kxq, kxq_bs, kxs, kxs_bs, ki1, ki2, ki3,
                 r2a, r2b, r2c, u & 15, u >> 4, tid, smem);
    }
}

extern "C" void kernel_launch(void* const* d_in, const int* in_sizes, int n_in,
                              void* d_out, int out_size, void* d_ws, size_t ws_size,
                              hipStream_t stream) {
    const float* frames = (const float*)d_in[0];
    const float* W1 = (const float*)d_in[1]; const float* b1 = (const float*)d_in[2];
    const float* W2 = (const float*)d_in[3]; const float* b2 = (const float*)d_in[4];
    const float* W3 = (const float*)d_in[5]; const float* b3 = (const float*)d_in[6];
    const float* Wm = (const float*)d_in[7]; const float* bm = (const float*)d_in[8];
    const float* Wl = (const float*)d_in[9]; const float* bl = (const float*)d_in[10];
    float* out = (float*)d_out;

    const long M = (long)BB * NN;    // 8192
    float* ws = (float*)d_ws;
    float* G1b = ws; ws += M * 64;
    float* G2b = ws; ws += M * 128;
    float* G3b = ws; ws += M * 256;
    ushort* us = (ushort*)ws;
    ushort* s1h = us; us += M * 64;   ushort* s1l = us; us += M * 64;
    ushort* s2h = us; us += M * 128;  ushort* s2l = us; us += M * 128;
    ushort* s3h = us; us += M * 256;  ushort* s3l = us; us += M * 256;
    ushort* w1h = us; us += 4096;     ushort* w1l = us; us += 4096;
    ushort* w2h = us; us += 16384;    ushort* w2l = us; us += 16384;
    ushort* w3h = us; us += 65536;    ushort* w3l = us; us += 65536;
    ushort* w2fh = us; us += 8192;    ushort* w2fl = us; us += 8192;
    ushort* w3fh = us; us += 32768;   ushort* w3fl = us; us += 32768;
    ushort* wmh = us; us += 16384;    ushort* wml = us; us += 16384;
    const long BNK = M * KNN;
    int* ip = (int*)us;
    int* idx1w = ip; ip += 7 * BNK;
    int* idx2w = ip; ip += 7 * BNK;
    int* idx3w = ip; ip += 7 * BNK;

    double ra = 4.0 + 1e-6, rb = 8.0 + 1e-6, rc = 12.0 + 1e-6;
    float r2a = (float)(ra * ra), r2b = (float)(rb * rb), r2c = (float)(rc * rc);

    const int FB = SEQ * NN * 3;
    const int OB = 6 * NN * 3;

    convW_kernel<<<560, 256, 0, stream>>>(W1, W2, W3, Wm,
                                          w1h, w1l, w2h, w2l, w3h, w3l,
                                          w2fh, w2fl, w3fh, w3fl, wmh, wml);
    knn_kernel<<<dim3(NN / QB, BB, 7), 256, 0, stream>>>(
        frames, FB, nullptr, 0, idx1w, idx2w, idx3w, r2a, r2b, r2c, 1);

    for (int t = 0; t < SEQ; ++t) {
        const float* xq; int xq_bs;
        const float* xs; int xs_bs;
        if (t < 6)       { xq = frames + (long)t * NN * 3;        xq_bs = FB; }
        else if (t == 6) { xq = frames + 5L * NN * 3;             xq_bs = FB; }
        else             { xq = out + (long)(t - 7) * NN * 3;     xq_bs = OB; }
        if (t == 0)      { xs = xq;                               xs_bs = xq_bs; }
        else if (t <= 6) { xs = frames + (long)(t - 1) * NN * 3;  xs_bs = FB; }
        else if (t == 7) { xs = frames + 5L * NN * 3;             xs_bs = FB; }
        else             { xs = out + (long)(t - 8) * NN * 3;     xs_bs = OB; }

        int slot = (t <= 6) ? t : 0;   // t>=7 uses slot 0 (written by fused knn)
        int* i1 = idx1w + slot * BNK;
        int* i2 = idx2w + slot * BNK;
        int* i3 = idx3w + slot * BNK;

        int do_head = (t >= 6);
        float* xnext = do_head ? out + (long)(t - 6) * NN * 3 : nullptr;

        if (t == 0)
            cells_kernel<true><<<BB * NN / PB, 512, 0, stream>>>(
                xq, xq_bs, xs, xs_bs, i1, i2, i3,
                G1b, G2b, G3b, s1h, s1l, s2h, s2l, s3h, s3l,
                W1, b1, W2, b2, W3, b3,
                w2fh, w2fl, w3fh, w3fl, wmh, wml, bm,
                Wl, bl, xnext, OB, do_head);
        else
            cells_kernel<false><<<BB * NN / PB, 512, 0, stream>>>(
                xq, xq_bs, xs, xs_bs, i1, i2, i3,
                G1b, G2b, G3b, s1h, s1l, s2h, s2l, s3h, s3l,
                W1, b1, W2, b2, W3, b3,
                w2fh, w2fl, w3fh, w3fl, wmh, wml, bm,
                Wl, bl, xnext, OB, do_head);

        // G for step t+1 (+ knn for step t+1 when t+1 >= 7)
        if (t < SEQ - 1) {
            bool dk = (t + 1 >= 7);
            const float* kxq = frames; int kxq_bs = FB;
            const float* kxs = frames; int kxs_bs = FB;
            if (dk) {
                kxq = out + (long)(t + 1 - 7) * NN * 3; kxq_bs = OB;
                if (t + 1 == 7) { kxs = frames + 5L * NN * 3; kxs_bs = FB; }
                else            { kxs = out + (long)(t + 1 - 8) * NN * 3; kxs_bs = OB; }
            }
            gemmG_knn_kernel<<<448 + (dk ? 256 : 0), 256, 0, stream>>>(
                s1h, s1l, s2h, s2l, s3h, s3l,
                w1h, w1l, w2h, w2l, w3h, w3l,
                G1b, G2b, G3b,
                kxq, kxq_bs, kxs, kxs_bs,
                idx1w, idx2w, idx3w, r2a, r2b, r2c);
        }
    }
}

// Round 13
// 559.755 us; speedup vs baseline: 1.0618x; 1.0584x over previous
//
#include <hip/hip_runtime.h>
#include <math.h>

#define BB 16
#define NN 512
#define KNN 8
#define SEQ 12
#define TQ 8            // knn: threads per query
#define QB 32           // knn: queries per block (TQ*QB = 256 threads)
#define PB 16           // cells: points per block

typedef __attribute__((ext_vector_type(8))) short bf8_t;   // 8 bf16 (4 VGPRs)
typedef __attribute__((ext_vector_type(4))) float f4_t;    // MFMA acc

__device__ __forceinline__ ushort f2b(float x) {           // fp32 -> bf16 RNE
    uint u = __float_as_uint(x);
    return (ushort)((u + 0x7fffu + ((u >> 16) & 1u)) >> 16);
}
__device__ __forceinline__ float b2f(ushort h) {
    return __uint_as_float((uint)h << 16);
}
// 8 consecutive fp32 -> hi/lo bf16 fragments (used only in head phase)
__device__ __forceinline__ void cvt8(const float* __restrict__ p,
                                     bf8_t& h, bf8_t& l) {
    float4 x0 = *(const float4*)p;
    float4 x1 = *(const float4*)(p + 4);
    float v[8] = {x0.x, x0.y, x0.z, x0.w, x1.x, x1.y, x1.z, x1.w};
#pragma unroll
    for (int i = 0; i < 8; ++i) {
        ushort hh = f2b(v[i]);
        h[i] = (short)hh;
        l[i] = (short)f2b(v[i] - b2f(hh));
    }
}

// ---------------------------------------------------------------------------
// KNN (warm=1: batched warmup over blockIdx.z; warm=0: single step) —
// unchanged, verified correct, conflict-free layout.
// ---------------------------------------------------------------------------
__global__ __launch_bounds__(256) void knn_kernel(
        const float* __restrict__ xq, int xq_bs,
        const float* __restrict__ xs, int xs_bs,
        int* __restrict__ idx1, int* __restrict__ idx2, int* __restrict__ idx3,
        float r2a, float r2b, float r2c, int warm) {
    __shared__ float s[NN * 3 + NN / 64];
    __shared__ float cd[QB][TQ][KNN + 1];
    __shared__ int   ci[QB][TQ][KNN + 1];
    int b = blockIdx.y;
    const float* xqp; const float* xsp; long iofs;
    if (warm) {
        int z = blockIdx.z;
        int qz = z < 5 ? z : 5;
        int sz = z - 1 < 0 ? 0 : z - 1;
        xqp = xq + (long)qz * NN * 3;
        xsp = xq + (long)sz * NN * 3;
        xs_bs = xq_bs;
        iofs = (long)z * BB * NN * KNN;
    } else {
        xqp = xq; xsp = xs; iofs = 0;
    }

    for (int j = threadIdx.x; j < NN; j += 256) {
        const float* p = xsp + (long)b * xs_bs + j * 3;
        int o = 3 * j + (j >> 6);
        s[o + 0] = p[0]; s[o + 1] = p[1]; s[o + 2] = p[2];
    }
    __syncthreads();

    int qi  = threadIdx.x / TQ;
    int sub = threadIdx.x % TQ;
    int n = blockIdx.x * QB + qi;
    const float* q = xqp + (long)b * xq_bs + n * 3;
    float qx = q[0], qy = q[1], qz2 = q[2];

    float bd[KNN];
    int   bi[KNN];
#pragma unroll
    for (int k = 0; k < KNN; ++k) { bd[k] = 1e30f; bi[k] = 0; }

    int j0 = sub * (NN / TQ);
    int sbase = 3 * j0 + sub;
#pragma unroll 4
    for (int jj = 0; jj < NN / TQ; ++jj) {
        float dx = s[sbase + 3 * jj + 0] - qx;
        float dy = s[sbase + 3 * jj + 1] - qy;
        float dz = s[sbase + 3 * jj + 2] - qz2;
        float d2 = fmaf(dx, dx, fmaf(dy, dy, dz * dz));
        if (d2 < bd[KNN - 1]) {
            bd[KNN - 1] = d2; bi[KNN - 1] = j0 + jj;
#pragma unroll
            for (int k = KNN - 1; k >= 1; --k) {
                if (bd[k] < bd[k - 1]) {
                    float td = bd[k]; bd[k] = bd[k - 1]; bd[k - 1] = td;
                    int   ti = bi[k]; bi[k] = bi[k - 1]; bi[k - 1] = ti;
                }
            }
        }
    }

#pragma unroll
    for (int k = 0; k < KNN; ++k) { cd[qi][sub][k] = bd[k]; ci[qi][sub][k] = bi[k]; }
    cd[qi][sub][KNN] = 1e30f; ci[qi][sub][KNN] = 0x7fffffff;
    __syncthreads();

    for (int stride = TQ / 2; stride >= 1; stride >>= 1) {
        if (sub < stride) {
            float rd[KNN]; int ri[KNN];
            int ia = 0, ib = 0;
#pragma unroll
            for (int k = 0; k < KNN; ++k) {
                float da = cd[qi][sub][ia], db = cd[qi][sub + stride][ib];
                int   ja = ci[qi][sub][ia], jb = ci[qi][sub + stride][ib];
                bool ta = (da < db) || (da == db && ja < jb);
                rd[k] = ta ? da : db; ri[k] = ta ? ja : jb;
                ia += ta ? 1 : 0; ib += ta ? 0 : 1;
            }
#pragma unroll
            for (int k = 0; k < KNN; ++k) { cd[qi][sub][k] = rd[k]; ci[qi][sub][k] = ri[k]; }
        }
        __syncthreads();
    }

    if (sub == 0) {
        long base = iofs + ((long)(b * NN + n)) * KNN;
        int i0 = ci[qi][0][0];
#pragma unroll
        for (int k = 0; k < KNN; ++k) {
            float d = cd[qi][0][k]; int j = ci[qi][0][k];
            idx1[base + k] = (d <= r2a) ? j : i0;
            idx2[base + k] = (d <= r2b) ? j : i0;
            idx3[base + k] = (d <= r2c) ? j : i0;
        }
    }
}

// ---------------------------------------------------------------------------
// One-time weight conversion to transposed split-bf16.
// ---------------------------------------------------------------------------
__global__ __launch_bounds__(256) void convW_kernel(
        const float* __restrict__ W1, const float* __restrict__ W2,
        const float* __restrict__ W3, const float* __restrict__ Wm,
        ushort* __restrict__ w1h, ushort* __restrict__ w1l,
        ushort* __restrict__ w2h, ushort* __restrict__ w2l,
        ushort* __restrict__ w3h, ushort* __restrict__ w3l,
        ushort* __restrict__ w2fh, ushort* __restrict__ w2fl,
        ushort* __restrict__ w3fh, ushort* __restrict__ w3fl,
        ushort* __restrict__ wmh, ushort* __restrict__ wml) {
    int t = blockIdx.x * 256 + threadIdx.x;
    float v; ushort* ph; ushort* pl; int idx;
    if (t < 4096)        { int n = t >> 6, k = t & 63;
        v = W1[(3 + k) * 64 + n];   ph = w1h;  pl = w1l;  idx = t; }
    else if (t < 20480)  { int u = t - 4096, n = u >> 7, k = u & 127;
        v = W2[(67 + k) * 128 + n]; ph = w2h;  pl = w2l;  idx = u; }
    else if (t < 86016)  { int u = t - 20480, n = u >> 8, k = u & 255;
        v = W3[(131 + k) * 256 + n]; ph = w3h; pl = w3l;  idx = u; }
    else if (t < 94208)  { int u = t - 86016, n = u >> 6, k = u & 63;
        v = W2[(3 + k) * 128 + n];  ph = w2fh; pl = w2fl; idx = u; }
    else if (t < 126976) { int u = t - 94208, n = u >> 7, k = u & 127;
        v = W3[(3 + k) * 256 + n];  ph = w3fh; pl = w3fl; idx = u; }
    else if (t < 143360) { int u = t - 126976, n = u >> 8, k = u & 255;
        v = Wm[k * 64 + n];         ph = wmh;  pl = wml;  idx = u; }
    else return;
    ushort h = f2b(v);
    ph[idx] = h; pl[idx] = f2b(v - b2f(h));
}

// ---------------------------------------------------------------------------
// Kernel A: combines on VALU, bases on MFMA with LDS-staged split-bf16.
// Compact lifetime-overlay pool = 31488 B (4 blocks/CU, wave-limited).
// do_g=0 (last step): skip all s*h/s*l global stores (no gemmG follows).
// ---------------------------------------------------------------------------
template<bool FIRST>
__global__ __launch_bounds__(512, 4) void cells_kernel(
        const float* __restrict__ xq, int xq_bs,
        const float* __restrict__ xs, int xs_bs,
        const int* __restrict__ i1, const int* __restrict__ i2,
        const int* __restrict__ i3,
        const float* __restrict__ G1p, const float* __restrict__ G2p,
        const float* __restrict__ G3p,
        ushort* __restrict__ s1h, ushort* __restrict__ s1l,
        ushort* __restrict__ s2h, ushort* __restrict__ s2l,
        ushort* __restrict__ s3h, ushort* __restrict__ s3l,
        const float* __restrict__ W1, const float* __restrict__ b1,
        const float* __restrict__ W2, const float* __restrict__ b2,
        const float* __restrict__ W3, const float* __restrict__ b3,
        const ushort* __restrict__ w2fh, const ushort* __restrict__ w2fl,
        const ushort* __restrict__ w3fh, const ushort* __restrict__ w3fl,
        const ushort* __restrict__ wmh, const ushort* __restrict__ wml,
        const float* __restrict__ bm,
        const float* __restrict__ Wl, const float* __restrict__ bl,
        float* __restrict__ xnext, int xn_bs, int do_head, int do_g) {
    // Compact pool (31488 B), lifetimes:
    //  [0,4608)      dsp  (P0->P5; hs overlays in P6)
    //  [4608,6144)   jss  (P0 -> g3 prefetch)
    //  [6144,14848)  s2H/s2L [16][136]u  (P3->P4)
    //  [14848,19456) s1H/s1L [16][72]u   (P1->P2; s3b overlays from P4)
    //  [19456,27904) s2s fp32 [16][132]  (P2->P3; s3b overlays from P4)
    //  [14848,31488) s3b fp32 [16][260]  (P4->P5/P6)
    __shared__ __attribute__((aligned(16))) char pool[31488];
    float*  dspf = (float*)pool;
    int*    jssp = (int*)(pool + 4608);
    ushort* s2H  = (ushort*)(pool + 6144);
    ushort* s2L  = (ushort*)(pool + 10496);
    ushort* s1H  = (ushort*)(pool + 14848);
    ushort* s1L  = (ushort*)(pool + 17152);
    float*  s2sp = (float*)(pool + 19456);
    float*  s3bp = (float*)(pool + 14848);     // overlays s1H/s1L + s2s
    float*  hsp  = (float*)pool;               // [16][64], overlays dsp (P6)

    const int tid = threadIdx.x;
    const int blk = blockIdx.x;          // 0..511
    const int xcd = blk & 7, slot = blk >> 3;
    const int b   = xcd * 2 + (slot >> 5);     // batch <-> XCD affinity
    const int n0  = (slot & 31) << 4;
    const long row0 = (long)b * NN + n0;
    const long bN = (long)b * NN;
    const int wv = tid >> 6, lane = tid & 63;
    const int fm = lane & 15, quad = lane >> 4;

    // P0: neighbor indices + displacements
    for (int t = tid; t < 3 * PB * KNN; t += 512) {
        int r = t >> 7, rem = t & 127, p = rem >> 3, k = rem & 7;
        const int* ix = (r == 0) ? i1 : ((r == 1) ? i2 : i3);
        int j = ix[(row0 + p) * KNN + k];
        jssp[t] = j;
        const float* sp = xs + (long)b * xs_bs + j * 3;
        const float* qp = xq + (long)b * xq_bs + (n0 + p) * 3;
        dspf[t * 3 + 0] = sp[0] - qp[0];
        dspf[t * 3 + 1] = sp[1] - qp[1];
        dspf[t * 3 + 2] = sp[2] - qp[2];
    }
    __syncthreads();

    // P1: cell1 combine -> split-bf16 to LDS (+ global when do_g)
    {
        int co = tid & 63, q = tid >> 6;
        float g1r[2][KNN];
        if (!FIRST) {
#pragma unroll
            for (int r = 0; r < 2; ++r)
#pragma unroll
                for (int k = 0; k < KNN; ++k)
                    g1r[r][k] = G1p[(bN + jssp[(2 * q + r) * 8 + k]) * 64 + co];
        }
        float wx = W1[co], wy = W1[64 + co], wz = W1[128 + co];
        float bz = b1[co];
#pragma unroll
        for (int r = 0; r < 2; ++r) {
            int p = 2 * q + r;
            float acc = -1e30f;
#pragma unroll
            for (int k = 0; k < KNN; ++k) {
                int di = (p * 8 + k) * 3;
                float v = fmaf(dspf[di + 0], wx, bz);
                v = fmaf(dspf[di + 1], wy, v);
                v = fmaf(dspf[di + 2], wz, v);
                if (!FIRST) v += g1r[r][k];
                acc = fmaxf(acc, v);
            }
            ushort h = f2b(acc);
            ushort l = f2b(acc - b2f(h));
            if (do_g) {
                s1h[(row0 + p) * 64 + co] = h;
                s1l[(row0 + p) * 64 + co] = l;
            }
            s1H[p * 72 + co] = h;
            s1L[p * 72 + co] = l;
        }
    }
    __syncthreads();

    // G2 gathers prefetched (consumed in P3, hidden behind P2 MFMA)
    float4 g2r[KNN];
    {
        int c4 = tid & 31, g = tid >> 5;
        if (!FIRST) {
#pragma unroll
            for (int k = 0; k < KNN; ++k)
                g2r[k] = ((const float4*)G2p)[(bN + jssp[(16 + g) * 8 + k]) * 32 + c4];
        }
    }

    // P2: base2 = s1 @ W2f + b2 on MFMA (A-frags from LDS bf16, no cvt)
    {
        int col = wv * 16 + fm;
        float bz = b2[col];
        f4_t acc = {bz, bz, bz, bz};
#pragma unroll
        for (int k0 = 0; k0 < 64; k0 += 32) {
            bf8_t ah = *(const bf8_t*)(s1H + fm * 72 + k0 + quad * 8);
            bf8_t al = *(const bf8_t*)(s1L + fm * 72 + k0 + quad * 8);
            bf8_t bh = *(const bf8_t*)(w2fh + col * 64 + k0 + quad * 8);
            bf8_t bl = *(const bf8_t*)(w2fl + col * 64 + k0 + quad * 8);
            acc = __builtin_amdgcn_mfma_f32_16x16x32_bf16(ah, bh, acc, 0, 0, 0);
            acc = __builtin_amdgcn_mfma_f32_16x16x32_bf16(ah, bl, acc, 0, 0, 0);
            acc = __builtin_amdgcn_mfma_f32_16x16x32_bf16(al, bh, acc, 0, 0, 0);
        }
#pragma unroll
        for (int r = 0; r < 4; ++r) s2sp[(quad * 4 + r) * 132 + col] = acc[r];
    }
    __syncthreads();

    // P3: combine2 -> split-bf16 to LDS (+ global when do_g)
    {
        int c4 = tid & 31, g = tid >> 5;
        float4 bse = *(float4*)&s2sp[g * 132 + c4 * 4];
        float4 wx = ((const float4*)W2)[c4];
        float4 wy = ((const float4*)(W2 + 128))[c4];
        float4 wz = ((const float4*)(W2 + 256))[c4];
        float4 m = make_float4(-1e30f, -1e30f, -1e30f, -1e30f);
#pragma unroll
        for (int k = 0; k < KNN; ++k) {
            int di = ((16 + g) * 8 + k) * 3;
            float dx = dspf[di + 0], dy = dspf[di + 1], dz = dspf[di + 2];
            float4 v;
            v.x = fmaf(dz, wz.x, fmaf(dy, wy.x, fmaf(dx, wx.x, bse.x)));
            v.y = fmaf(dz, wz.y, fmaf(dy, wy.y, fmaf(dx, wx.y, bse.y)));
            v.z = fmaf(dz, wz.z, fmaf(dy, wy.z, fmaf(dx, wx.z, bse.z)));
            v.w = fmaf(dz, wz.w, fmaf(dy, wy.w, fmaf(dx, wx.w, bse.w)));
            if (!FIRST) {
                v.x += g2r[k].x; v.y += g2r[k].y;
                v.z += g2r[k].z; v.w += g2r[k].w;
            }
            m.x = fmaxf(m.x, v.x); m.y = fmaxf(m.y, v.y);
            m.z = fmaxf(m.z, v.z); m.w = fmaxf(m.w, v.w);
        }
        ushort4 mh, ml;
        mh.x = f2b(m.x); ml.x = f2b(m.x - b2f(mh.x));
        mh.y = f2b(m.y); ml.y = f2b(m.y - b2f(mh.y));
        mh.z = f2b(m.z); ml.z = f2b(m.z - b2f(mh.z));
        mh.w = f2b(m.w); ml.w = f2b(m.w - b2f(mh.w));
        if (do_g) {
            *(ushort4*)&s2h[(row0 + g) * 128 + c4 * 4] = mh;
            *(ushort4*)&s2l[(row0 + g) * 128 + c4 * 4] = ml;
        }
        *(ushort4*)(s2H + g * 136 + c4 * 4) = mh;
        *(ushort4*)(s2L + g * 136 + c4 * 4) = ml;
    }
    __syncthreads();

    // G3 gathers prefetched (consumed in P5, hidden behind P4 MFMA)
    float4 g3r[2][KNN];
    {
        int c4 = tid & 63, g = tid >> 6;
        if (!FIRST) {
#pragma unroll
            for (int r = 0; r < 2; ++r)
#pragma unroll
                for (int k = 0; k < KNN; ++k)
                    g3r[r][k] = ((const float4*)G3p)[(bN + jssp[(32 + 2 * g + r) * 8 + k]) * 64 + c4];
        }
    }

    // P4: base3 = s2 @ W3f + b3 on MFMA (A from LDS bf16) -> s3b
    {
        int col0 = wv * 16 + fm, col1 = (wv + 8) * 16 + fm;
        float bz0 = b3[col0], bz1 = b3[col1];
        f4_t a0 = {bz0, bz0, bz0, bz0};
        f4_t a1 = {bz1, bz1, bz1, bz1};
#pragma unroll
        for (int k0 = 0; k0 < 128; k0 += 32) {
            bf8_t ah = *(const bf8_t*)(s2H + fm * 136 + k0 + quad * 8);
            bf8_t al = *(const bf8_t*)(s2L + fm * 136 + k0 + quad * 8);
            bf8_t b0h = *(const bf8_t*)(w3fh + col0 * 128 + k0 + quad * 8);
            bf8_t b0l = *(const bf8_t*)(w3fl + col0 * 128 + k0 + quad * 8);
            bf8_t b1h = *(const bf8_t*)(w3fh + col1 * 128 + k0 + quad * 8);
            bf8_t b1l = *(const bf8_t*)(w3fl + col1 * 128 + k0 + quad * 8);
            a0 = __builtin_amdgcn_mfma_f32_16x16x32_bf16(ah, b0h, a0, 0, 0, 0);
            a0 = __builtin_amdgcn_mfma_f32_16x16x32_bf16(ah, b0l, a0, 0, 0, 0);
            a0 = __builtin_amdgcn_mfma_f32_16x16x32_bf16(al, b0h, a0, 0, 0, 0);
            a1 = __builtin_amdgcn_mfma_f32_16x16x32_bf16(ah, b1h, a1, 0, 0, 0);
            a1 = __builtin_amdgcn_mfma_f32_16x16x32_bf16(ah, b1l, a1, 0, 0, 0);
            a1 = __builtin_amdgcn_mfma_f32_16x16x32_bf16(al, b1h, a1, 0, 0, 0);
        }
#pragma unroll
        for (int r = 0; r < 4; ++r) {
            s3bp[(quad * 4 + r) * 260 + col0] = a0[r];
            s3bp[(quad * 4 + r) * 260 + col1] = a1[r];
        }
    }
    __syncthreads();

    // P5: combine3 -> split-bf16 to global (when do_g); fp32 back into s3b
    {
        int c4 = tid & 63, g = tid >> 6;
        float4 wx = ((const float4*)W3)[c4];
        float4 wy = ((const float4*)(W3 + 256))[c4];
        float4 wz = ((const float4*)(W3 + 512))[c4];
#pragma unroll
        for (int r = 0; r < 2; ++r) {
            int p = 2 * g + r;
            float4 bse = *(float4*)&s3bp[p * 260 + c4 * 4];
            float4 m = make_float4(-1e30f, -1e30f, -1e30f, -1e30f);
#pragma unroll
            for (int k = 0; k < KNN; ++k) {
                int di = ((32 + p) * 8 + k) * 3;
                float dx = dspf[di + 0], dy = dspf[di + 1], dz = dspf[di + 2];
                float4 v;
                v.x = fmaf(dz, wz.x, fmaf(dy, wy.x, fmaf(dx, wx.x, bse.x)));
                v.y = fmaf(dz, wz.y, fmaf(dy, wy.y, fmaf(dx, wx.y, bse.y)));
                v.z = fmaf(dz, wz.z, fmaf(dy, wy.z, fmaf(dx, wx.z, bse.z)));
                v.w = fmaf(dz, wz.w, fmaf(dy, wy.w, fmaf(dx, wx.w, bse.w)));
                if (!FIRST) {
                    v.x += g3r[r][k].x; v.y += g3r[r][k].y;
                    v.z += g3r[r][k].z; v.w += g3r[r][k].w;
                }
                m.x = fmaxf(m.x, v.x); m.y = fmaxf(m.y, v.y);
                m.z = fmaxf(m.z, v.z); m.w = fmaxf(m.w, v.w);
            }
            *(float4*)&s3bp[p * 260 + c4 * 4] = m;   // in place (thread-owned)
            if (do_g) {
                ushort4 mh, ml;
                mh.x = f2b(m.x); ml.x = f2b(m.x - b2f(mh.x));
                mh.y = f2b(m.y); ml.y = f2b(m.y - b2f(mh.y));
                mh.z = f2b(m.z); ml.z = f2b(m.z - b2f(mh.z));
                mh.w = f2b(m.w); ml.w = f2b(m.w - b2f(mh.w));
                *(ushort4*)&s3h[(row0 + p) * 256 + c4 * 4] = mh;
                *(ushort4*)&s3l[(row0 + p) * 256 + c4 * 4] = ml;
            }
        }
    }

    // P6: head — h = relu(s3 @ Wm + bm) on MFMA (cvt from fp32 s3b), motion
    if (do_head) {
        __syncthreads();
        if (wv < 4) {
            int col = wv * 16 + fm;
            float bz = bm[col];
            f4_t acc = {bz, bz, bz, bz};
#pragma unroll
            for (int k0 = 0; k0 < 256; k0 += 32) {
                bf8_t ah, al; cvt8(&s3bp[fm * 260 + k0 + quad * 8], ah, al);
                bf8_t bh = *(const bf8_t*)(wmh + col * 256 + k0 + quad * 8);
                bf8_t bl = *(const bf8_t*)(wml + col * 256 + k0 + quad * 8);
                acc = __builtin_amdgcn_mfma_f32_16x16x32_bf16(ah, bh, acc, 0, 0, 0);
                acc = __builtin_amdgcn_mfma_f32_16x16x32_bf16(ah, bl, acc, 0, 0, 0);
                acc = __builtin_amdgcn_mfma_f32_16x16x32_bf16(al, bh, acc, 0, 0, 0);
            }
#pragma unroll
            for (int r = 0; r < 4; ++r)
                hsp[(quad * 4 + r) * 64 + col] = fmaxf(acc[r], 0.f);
        }
        __syncthreads();
        if (tid < PB * 3) {
            int p = tid / 3, d = tid % 3;
            float m = bl[d];
#pragma unroll 4
            for (int c = 0; c < 64; ++c)
                m = fmaf(hsp[p * 64 + c], Wl[c * 3 + d], m);
            const float* qp = xq + (long)b * xq_bs + (n0 + p) * 3;
            xnext[(long)b * xn_bs + (n0 + p) * 3 + d] = qp[d] + m;
        }
    }
}

// ---------------------------------------------------------------------------
// Tiled MFMA GEMM tile (unchanged — verified).
// ---------------------------------------------------------------------------
template<int N>
__device__ __forceinline__ void gemmTile(
        const ushort* __restrict__ Ah, const ushort* __restrict__ Al,
        const ushort* __restrict__ Bh, const ushort* __restrict__ Bl,
        float* __restrict__ G, int rb, int cb, int tid, ushort* lds) {
    const int row0 = rb * 128, c0 = cb * 64;
    ushort* ah = lds;
    ushort* al = lds + 128 * 40;
    ushort* bh = lds + 256 * 40;
    ushort* bl = lds + 320 * 40;
    const int wv = tid >> 6, lane = tid & 63;
    const int m = lane & 15, quad = lane >> 4;
    const int wm0 = wv * 32;
    const int lr = tid >> 2, ls = (tid & 3) * 8;

    f4_t acc[2][4];
#pragma unroll
    for (int rt = 0; rt < 2; ++rt)
#pragma unroll
        for (int ct = 0; ct < 4; ++ct) acc[rt][ct] = (f4_t){0.f, 0.f, 0.f, 0.f};

    bf8_t pah0, pah1, pal0, pal1, pbh, pbl;
    pah0 = *(const bf8_t*)(Ah + (long)(row0 + lr) * N + ls);
    pah1 = *(const bf8_t*)(Ah + (long)(row0 + 64 + lr) * N + ls);
    pal0 = *(const bf8_t*)(Al + (long)(row0 + lr) * N + ls);
    pal1 = *(const bf8_t*)(Al + (long)(row0 + 64 + lr) * N + ls);
    pbh  = *(const bf8_t*)(Bh + (long)(c0 + lr) * N + ls);
    pbl  = *(const bf8_t*)(Bl + (long)(c0 + lr) * N + ls);

    for (int k0 = 0; k0 < N; k0 += 32) {
        if (k0) __syncthreads();
        *(bf8_t*)(ah + lr * 40 + ls) = pah0;
        *(bf8_t*)(ah + (64 + lr) * 40 + ls) = pah1;
        *(bf8_t*)(al + lr * 40 + ls) = pal0;
        *(bf8_t*)(al + (64 + lr) * 40 + ls) = pal1;
        *(bf8_t*)(bh + lr * 40 + ls) = pbh;
        *(bf8_t*)(bl + lr * 40 + ls) = pbl;
        __syncthreads();
        if (k0 + 32 < N) {
            int kn = k0 + 32;
            pah0 = *(const bf8_t*)(Ah + (long)(row0 + lr) * N + kn + ls);
            pah1 = *(const bf8_t*)(Ah + (long)(row0 + 64 + lr) * N + kn + ls);
            pal0 = *(const bf8_t*)(Al + (long)(row0 + lr) * N + kn + ls);
            pal1 = *(const bf8_t*)(Al + (long)(row0 + 64 + lr) * N + kn + ls);
            pbh  = *(const bf8_t*)(Bh + (long)(c0 + lr) * N + kn + ls);
            pbl  = *(const bf8_t*)(Bl + (long)(c0 + lr) * N + kn + ls);
        }
        bf8_t a0h = *(const bf8_t*)(ah + (wm0 + m) * 40 + quad * 8);
        bf8_t a0l = *(const bf8_t*)(al + (wm0 + m) * 40 + quad * 8);
        bf8_t a1h = *(const bf8_t*)(ah + (wm0 + 16 + m) * 40 + quad * 8);
        bf8_t a1l = *(const bf8_t*)(al + (wm0 + 16 + m) * 40 + quad * 8);
#pragma unroll
        for (int ct = 0; ct < 4; ++ct) {
            bf8_t bth = *(const bf8_t*)(bh + (ct * 16 + m) * 40 + quad * 8);
            bf8_t btl = *(const bf8_t*)(bl + (ct * 16 + m) * 40 + quad * 8);
            acc[0][ct] = __builtin_amdgcn_mfma_f32_16x16x32_bf16(a0h, bth, acc[0][ct], 0, 0, 0);
            acc[0][ct] = __builtin_amdgcn_mfma_f32_16x16x32_bf16(a0h, btl, acc[0][ct], 0, 0, 0);
            acc[0][ct] = __builtin_amdgcn_mfma_f32_16x16x32_bf16(a0l, bth, acc[0][ct], 0, 0, 0);
            acc[1][ct] = __builtin_amdgcn_mfma_f32_16x16x32_bf16(a1h, bth, acc[1][ct], 0, 0, 0);
            acc[1][ct] = __builtin_amdgcn_mfma_f32_16x16x32_bf16(a1h, btl, acc[1][ct], 0, 0, 0);
            acc[1][ct] = __builtin_amdgcn_mfma_f32_16x16x32_bf16(a1l, bth, acc[1][ct], 0, 0, 0);
        }
    }
#pragma unroll
    for (int rt = 0; rt < 2; ++rt)
#pragma unroll
        for (int ct = 0; ct < 4; ++ct) {
            int col = c0 + ct * 16 + m;
#pragma unroll
            for (int r = 0; r < 4; ++r)
                G[(long)(row0 + wm0 + rt * 16 + quad * 4 + r) * N + col] = acc[rt][ct][r];
        }
}

__global__ __launch_bounds__(256) void gemmG_kernel(
        const ushort* __restrict__ s1h, const ushort* __restrict__ s1l,
        const ushort* __restrict__ s2h, const ushort* __restrict__ s2l,
        const ushort* __restrict__ s3h, const ushort* __restrict__ s3l,
        const ushort* __restrict__ w1h, const ushort* __restrict__ w1l,
        const ushort* __restrict__ w2h, const ushort* __restrict__ w2l,
        const ushort* __restrict__ w3h, const ushort* __restrict__ w3l,
        float* __restrict__ G1, float* __restrict__ G2,
        float* __restrict__ G3) {
    __shared__ ushort lds[384 * 40];
    int bx = blockIdx.x, tid = threadIdx.x;
    if (bx < 256) {
        int xcd = bx & 7, rem = bx >> 3;
        int rb = xcd * 8 + (rem & 7), cb = rem >> 3;
        gemmTile<256>(s3h, s3l, w3h, w3l, G3, rb, cb, tid, lds);
    } else if (bx < 384) {
        int u = bx - 256; int xcd = u & 7, rem = u >> 3;
        int rb = xcd * 8 + (rem & 7), cb = rem >> 3;
        gemmTile<128>(s2h, s2l, w2h, w2l, G2, rb, cb, tid, lds);
    } else {
        int u = bx - 384; int xcd = u & 7, j = u >> 3;
        gemmTile<64>(s1h, s1l, w1h, w1l, G1, xcd * 8 + j, 0, tid, lds);
    }
}

extern "C" void kernel_launch(void* const* d_in, const int* in_sizes, int n_in,
                              void* d_out, int out_size, void* d_ws, size_t ws_size,
                              hipStream_t stream) {
    const float* frames = (const float*)d_in[0];
    const float* W1 = (const float*)d_in[1]; const float* b1 = (const float*)d_in[2];
    const float* W2 = (const float*)d_in[3]; const float* b2 = (const float*)d_in[4];
    const float* W3 = (const float*)d_in[5]; const float* b3 = (const float*)d_in[6];
    const float* Wm = (const float*)d_in[7]; const float* bm = (const float*)d_in[8];
    const float* Wl = (const float*)d_in[9]; const float* bl = (const float*)d_in[10];
    float* out = (float*)d_out;

    const long M = (long)BB * NN;    // 8192
    float* ws = (float*)d_ws;
    float* G1b = ws; ws += M * 64;
    float* G2b = ws; ws += M * 128;
    float* G3b = ws; ws += M * 256;
    ushort* us = (ushort*)ws;
    ushort* s1h = us; us += M * 64;   ushort* s1l = us; us += M * 64;
    ushort* s2h = us; us += M * 128;  ushort* s2l = us; us += M * 128;
    ushort* s3h = us; us += M * 256;  ushort* s3l = us; us += M * 256;
    ushort* w1h = us; us += 4096;     ushort* w1l = us; us += 4096;
    ushort* w2h = us; us += 16384;    ushort* w2l = us; us += 16384;
    ushort* w3h = us; us += 65536;    ushort* w3l = us; us += 65536;
    ushort* w2fh = us; us += 8192;    ushort* w2fl = us; us += 8192;
    ushort* w3fh = us; us += 32768;   ushort* w3fl = us; us += 32768;
    ushort* wmh = us; us += 16384;    ushort* wml = us; us += 16384;
    const long BNK = M * KNN;
    int* ip = (int*)us;
    int* idx1w = ip; ip += 7 * BNK;
    int* idx2w = ip; ip += 7 * BNK;
    int* idx3w = ip; ip += 7 * BNK;

    double ra = 4.0 + 1e-6, rb = 8.0 + 1e-6, rc = 12.0 + 1e-6;
    float r2a = (float)(ra * ra), r2b = (float)(rb * rb), r2c = (float)(rc * rc);

    const int FB = SEQ * NN * 3;
    const int OB = 6 * NN * 3;

    convW_kernel<<<560, 256, 0, stream>>>(W1, W2, W3, Wm,
                                          w1h, w1l, w2h, w2l, w3h, w3l,
                                          w2fh, w2fl, w3fh, w3fl, wmh, wml);
    knn_kernel<<<dim3(NN / QB, BB, 7), 256, 0, stream>>>(
        frames, FB, nullptr, 0, idx1w, idx2w, idx3w, r2a, r2b, r2c, 1);

    for (int t = 0; t < SEQ; ++t) {
        const float* xq; int xq_bs;
        const float* xs; int xs_bs;
        if (t < 6)       { xq = frames + (long)t * NN * 3;        xq_bs = FB; }
        else if (t == 6) { xq = frames + 5L * NN * 3;             xq_bs = FB; }
        else             { xq = out + (long)(t - 7) * NN * 3;     xq_bs = OB; }
        if (t == 0)      { xs = xq;                               xs_bs = xq_bs; }
        else if (t <= 6) { xs = frames + (long)(t - 1) * NN * 3;  xs_bs = FB; }
        else if (t == 7) { xs = frames + 5L * NN * 3;             xs_bs = FB; }
        else             { xs = out + (long)(t - 8) * NN * 3;     xs_bs = OB; }

        int slot = (t <= 6) ? t : 0;    // t>=7 reuses slot 0
        int* i1 = idx1w + slot * BNK;
        int* i2 = idx2w + slot * BNK;
        int* i3 = idx3w + slot * BNK;

        if (t >= 7)
            knn_kernel<<<dim3(NN / QB, BB, 1), 256, 0, stream>>>(
                xq, xq_bs, xs, xs_bs, i1, i2, i3, r2a, r2b, r2c, 0);

        int do_head = (t >= 6);
        int do_g = (t < SEQ - 1);
        float* xnext = do_head ? out + (long)(t - 6) * NN * 3 : nullptr;

        if (t == 0)
            cells_kernel<true><<<BB * NN / PB, 512, 0, stream>>>(
                xq, xq_bs, xs, xs_bs, i1, i2, i3,
                G1b, G2b, G3b, s1h, s1l, s2h, s2l, s3h, s3l,
                W1, b1, W2, b2, W3, b3,
                w2fh, w2fl, w3fh, w3fl, wmh, wml, bm,
                Wl, bl, xnext, OB, do_head, do_g);
        else
            cells_kernel<false><<<BB * NN / PB, 512, 0, stream>>>(
                xq, xq_bs, xs, xs_bs, i1, i2, i3,
                G1b, G2b, G3b, s1h, s1l, s2h, s2l, s3h, s3l,
                W1, b1, W2, b2, W3, b3,
                w2fh, w2fl, w3fh, w3fl, wmh, wml, bm,
                Wl, bl, xnext, OB, do_head, do_g);

        // G for step t+1 on the matrix pipe
        if (t < SEQ - 1)
            gemmG_kernel<<<448, 256, 0, stream>>>(
                s1h, s1l, s2h, s2l, s3h, s3l,
                w1h, w1l, w2h, w2l, w3h, w3l,
                G1b, G2b, G3b);
    }
}

// Round 14
// 559.534 us; speedup vs baseline: 1.0622x; 1.0004x over previous
//
#include <hip/hip_runtime.h>
#include <math.h>

#define BB 16
#define NN 512
#define KNN 8
#define SEQ 12
#define TQ 16           // knn: threads per query (each scans NN/TQ = 32 pts)
#define QB 16           // knn: queries per block (TQ*QB = 256 threads)
#define PB 16           // cells: points per block

typedef __attribute__((ext_vector_type(8))) short bf8_t;   // 8 bf16 (4 VGPRs)
typedef __attribute__((ext_vector_type(4))) float f4_t;    // MFMA acc

__device__ __forceinline__ ushort f2b(float x) {           // fp32 -> bf16 RNE
    uint u = __float_as_uint(x);
    return (ushort)((u + 0x7fffu + ((u >> 16) & 1u)) >> 16);
}
__device__ __forceinline__ float b2f(ushort h) {
    return __uint_as_float((uint)h << 16);
}
// 8 consecutive fp32 -> hi/lo bf16 fragments (used only in head phase)
__device__ __forceinline__ void cvt8(const float* __restrict__ p,
                                     bf8_t& h, bf8_t& l) {
    float4 x0 = *(const float4*)p;
    float4 x1 = *(const float4*)(p + 4);
    float v[8] = {x0.x, x0.y, x0.z, x0.w, x1.x, x1.y, x1.z, x1.w};
#pragma unroll
    for (int i = 0; i < 8; ++i) {
        ushort hh = f2b(v[i]);
        h[i] = (short)hh;
        l[i] = (short)f2b(v[i] - b2f(hh));
    }
}

// ---------------------------------------------------------------------------
// KNN: TQ=16 threads/query scanning 32 points each -> 512 blocks (2/CU).
// LDS pad s[3j + (j>>5)]: bank = sub + 3*jj (97%32==1), same-sub queries
// broadcast -> conflict-free. 4-level lexicographic (d2,idx) merge = exact
// stable top-8 (order-independent of chunking).
// ---------------------------------------------------------------------------
__global__ __launch_bounds__(256) void knn_kernel(
        const float* __restrict__ xq, int xq_bs,
        const float* __restrict__ xs, int xs_bs,
        int* __restrict__ idx1, int* __restrict__ idx2, int* __restrict__ idx3,
        float r2a, float r2b, float r2c, int warm) {
    __shared__ float s[NN * 3 + NN / 32];
    __shared__ float cd[QB][TQ][KNN + 1];
    __shared__ int   ci[QB][TQ][KNN + 1];
    int b = blockIdx.y;
    const float* xqp; const float* xsp; long iofs;
    if (warm) {
        int z = blockIdx.z;
        int qz = z < 5 ? z : 5;
        int sz = z - 1 < 0 ? 0 : z - 1;
        xqp = xq + (long)qz * NN * 3;
        xsp = xq + (long)sz * NN * 3;
        xs_bs = xq_bs;
        iofs = (long)z * BB * NN * KNN;
    } else {
        xqp = xq; xsp = xs; iofs = 0;
    }

    for (int j = threadIdx.x; j < NN; j += 256) {
        const float* p = xsp + (long)b * xs_bs + j * 3;
        int o = 3 * j + (j >> 5);
        s[o + 0] = p[0]; s[o + 1] = p[1]; s[o + 2] = p[2];
    }
    __syncthreads();

    int qi  = threadIdx.x / TQ;
    int sub = threadIdx.x % TQ;
    int n = blockIdx.x * QB + qi;
    const float* q = xqp + (long)b * xq_bs + n * 3;
    float qx = q[0], qy = q[1], qz2 = q[2];

    float bd[KNN];
    int   bi[KNN];
#pragma unroll
    for (int k = 0; k < KNN; ++k) { bd[k] = 1e30f; bi[k] = 0; }

    int j0 = sub * (NN / TQ);
    int sbase = 3 * j0 + (j0 >> 5);      // chunk of 32 never crosses pad step
#pragma unroll 4
    for (int jj = 0; jj < NN / TQ; ++jj) {
        float dx = s[sbase + 3 * jj + 0] - qx;
        float dy = s[sbase + 3 * jj + 1] - qy;
        float dz = s[sbase + 3 * jj + 2] - qz2;
        float d2 = fmaf(dx, dx, fmaf(dy, dy, dz * dz));
        if (d2 < bd[KNN - 1]) {
            bd[KNN - 1] = d2; bi[KNN - 1] = j0 + jj;
#pragma unroll
            for (int k = KNN - 1; k >= 1; --k) {
                if (bd[k] < bd[k - 1]) {
                    float td = bd[k]; bd[k] = bd[k - 1]; bd[k - 1] = td;
                    int   ti = bi[k]; bi[k] = bi[k - 1]; bi[k - 1] = ti;
                }
            }
        }
    }

#pragma unroll
    for (int k = 0; k < KNN; ++k) { cd[qi][sub][k] = bd[k]; ci[qi][sub][k] = bi[k]; }
    cd[qi][sub][KNN] = 1e30f; ci[qi][sub][KNN] = 0x7fffffff;
    __syncthreads();

    for (int stride = TQ / 2; stride >= 1; stride >>= 1) {
        if (sub < stride) {
            float rd[KNN]; int ri[KNN];
            int ia = 0, ib = 0;
#pragma unroll
            for (int k = 0; k < KNN; ++k) {
                float da = cd[qi][sub][ia], db = cd[qi][sub + stride][ib];
                int   ja = ci[qi][sub][ia], jb = ci[qi][sub + stride][ib];
                bool ta = (da < db) || (da == db && ja < jb);
                rd[k] = ta ? da : db; ri[k] = ta ? ja : jb;
                ia += ta ? 1 : 0; ib += ta ? 0 : 1;
            }
#pragma unroll
            for (int k = 0; k < KNN; ++k) { cd[qi][sub][k] = rd[k]; ci[qi][sub][k] = ri[k]; }
        }
        __syncthreads();
    }

    if (sub == 0) {
        long base = iofs + ((long)(b * NN + n)) * KNN;
        int i0 = ci[qi][0][0];
#pragma unroll
        for (int k = 0; k < KNN; ++k) {
            float d = cd[qi][0][k]; int j = ci[qi][0][k];
            idx1[base + k] = (d <= r2a) ? j : i0;
            idx2[base + k] = (d <= r2b) ? j : i0;
            idx3[base + k] = (d <= r2c) ? j : i0;
        }
    }
}

// ---------------------------------------------------------------------------
// One-time weight conversion to transposed split-bf16.
// ---------------------------------------------------------------------------
__global__ __launch_bounds__(256) void convW_kernel(
        const float* __restrict__ W1, const float* __restrict__ W2,
        const float* __restrict__ W3, const float* __restrict__ Wm,
        ushort* __restrict__ w1h, ushort* __restrict__ w1l,
        ushort* __restrict__ w2h, ushort* __restrict__ w2l,
        ushort* __restrict__ w3h, ushort* __restrict__ w3l,
        ushort* __restrict__ w2fh, ushort* __restrict__ w2fl,
        ushort* __restrict__ w3fh, ushort* __restrict__ w3fl,
        ushort* __restrict__ wmh, ushort* __restrict__ wml) {
    int t = blockIdx.x * 256 + threadIdx.x;
    float v; ushort* ph; ushort* pl; int idx;
    if (t < 4096)        { int n = t >> 6, k = t & 63;
        v = W1[(3 + k) * 64 + n];   ph = w1h;  pl = w1l;  idx = t; }
    else if (t < 20480)  { int u = t - 4096, n = u >> 7, k = u & 127;
        v = W2[(67 + k) * 128 + n]; ph = w2h;  pl = w2l;  idx = u; }
    else if (t < 86016)  { int u = t - 20480, n = u >> 8, k = u & 255;
        v = W3[(131 + k) * 256 + n]; ph = w3h; pl = w3l;  idx = u; }
    else if (t < 94208)  { int u = t - 86016, n = u >> 6, k = u & 63;
        v = W2[(3 + k) * 128 + n];  ph = w2fh; pl = w2fl; idx = u; }
    else if (t < 126976) { int u = t - 94208, n = u >> 7, k = u & 127;
        v = W3[(3 + k) * 256 + n];  ph = w3fh; pl = w3fl; idx = u; }
    else if (t < 143360) { int u = t - 126976, n = u >> 8, k = u & 255;
        v = Wm[k * 64 + n];         ph = wmh;  pl = wml;  idx = u; }
    else return;
    ushort h = f2b(v);
    ph[idx] = h; pl[idx] = f2b(v - b2f(h));
}

// ---------------------------------------------------------------------------
// Kernel A: combines on VALU, bases on MFMA with LDS-staged split-bf16.
// Compact lifetime-overlay pool = 31488 B (4 blocks/CU). Unchanged from R13.
// ---------------------------------------------------------------------------
template<bool FIRST>
__global__ __launch_bounds__(512, 4) void cells_kernel(
        const float* __restrict__ xq, int xq_bs,
        const float* __restrict__ xs, int xs_bs,
        const int* __restrict__ i1, const int* __restrict__ i2,
        const int* __restrict__ i3,
        const float* __restrict__ G1p, const float* __restrict__ G2p,
        const float* __restrict__ G3p,
        ushort* __restrict__ s1h, ushort* __restrict__ s1l,
        ushort* __restrict__ s2h, ushort* __restrict__ s2l,
        ushort* __restrict__ s3h, ushort* __restrict__ s3l,
        const float* __restrict__ W1, const float* __restrict__ b1,
        const float* __restrict__ W2, const float* __restrict__ b2,
        const float* __restrict__ W3, const float* __restrict__ b3,
        const ushort* __restrict__ w2fh, const ushort* __restrict__ w2fl,
        const ushort* __restrict__ w3fh, const ushort* __restrict__ w3fl,
        const ushort* __restrict__ wmh, const ushort* __restrict__ wml,
        const float* __restrict__ bm,
        const float* __restrict__ Wl, const float* __restrict__ bl,
        float* __restrict__ xnext, int xn_bs, int do_head, int do_g) {
    __shared__ __attribute__((aligned(16))) char pool[31488];
    float*  dspf = (float*)pool;
    int*    jssp = (int*)(pool + 4608);
    ushort* s2H  = (ushort*)(pool + 6144);
    ushort* s2L  = (ushort*)(pool + 10496);
    ushort* s1H  = (ushort*)(pool + 14848);
    ushort* s1L  = (ushort*)(pool + 17152);
    float*  s2sp = (float*)(pool + 19456);
    float*  s3bp = (float*)(pool + 14848);     // overlays s1H/s1L + s2s
    float*  hsp  = (float*)pool;               // [16][64], overlays dsp (P6)

    const int tid = threadIdx.x;
    const int blk = blockIdx.x;          // 0..511
    const int xcd = blk & 7, slot = blk >> 3;
    const int b   = xcd * 2 + (slot >> 5);     // batch <-> XCD affinity
    const int n0  = (slot & 31) << 4;
    const long row0 = (long)b * NN + n0;
    const long bN = (long)b * NN;
    const int wv = tid >> 6, lane = tid & 63;
    const int fm = lane & 15, quad = lane >> 4;

    // P0: neighbor indices + displacements
    for (int t = tid; t < 3 * PB * KNN; t += 512) {
        int r = t >> 7, rem = t & 127, p = rem >> 3, k = rem & 7;
        const int* ix = (r == 0) ? i1 : ((r == 1) ? i2 : i3);
        int j = ix[(row0 + p) * KNN + k];
        jssp[t] = j;
        const float* sp = xs + (long)b * xs_bs + j * 3;
        const float* qp = xq + (long)b * xq_bs + (n0 + p) * 3;
        dspf[t * 3 + 0] = sp[0] - qp[0];
        dspf[t * 3 + 1] = sp[1] - qp[1];
        dspf[t * 3 + 2] = sp[2] - qp[2];
    }
    __syncthreads();

    // P1: cell1 combine -> split-bf16 to LDS (+ global when do_g)
    {
        int co = tid & 63, q = tid >> 6;
        float g1r[2][KNN];
        if (!FIRST) {
#pragma unroll
            for (int r = 0; r < 2; ++r)
#pragma unroll
                for (int k = 0; k < KNN; ++k)
                    g1r[r][k] = G1p[(bN + jssp[(2 * q + r) * 8 + k]) * 64 + co];
        }
        float wx = W1[co], wy = W1[64 + co], wz = W1[128 + co];
        float bz = b1[co];
#pragma unroll
        for (int r = 0; r < 2; ++r) {
            int p = 2 * q + r;
            float acc = -1e30f;
#pragma unroll
            for (int k = 0; k < KNN; ++k) {
                int di = (p * 8 + k) * 3;
                float v = fmaf(dspf[di + 0], wx, bz);
                v = fmaf(dspf[di + 1], wy, v);
                v = fmaf(dspf[di + 2], wz, v);
                if (!FIRST) v += g1r[r][k];
                acc = fmaxf(acc, v);
            }
            ushort h = f2b(acc);
            ushort l = f2b(acc - b2f(h));
            if (do_g) {
                s1h[(row0 + p) * 64 + co] = h;
                s1l[(row0 + p) * 64 + co] = l;
            }
            s1H[p * 72 + co] = h;
            s1L[p * 72 + co] = l;
        }
    }
    __syncthreads();

    // G2 gathers prefetched (consumed in P3, hidden behind P2 MFMA)
    float4 g2r[KNN];
    {
        int c4 = tid & 31, g = tid >> 5;
        if (!FIRST) {
#pragma unroll
            for (int k = 0; k < KNN; ++k)
                g2r[k] = ((const float4*)G2p)[(bN + jssp[(16 + g) * 8 + k]) * 32 + c4];
        }
    }

    // P2: base2 = s1 @ W2f + b2 on MFMA (A-frags from LDS bf16, no cvt)
    {
        int col = wv * 16 + fm;
        float bz = b2[col];
        f4_t acc = {bz, bz, bz, bz};
#pragma unroll
        for (int k0 = 0; k0 < 64; k0 += 32) {
            bf8_t ah = *(const bf8_t*)(s1H + fm * 72 + k0 + quad * 8);
            bf8_t al = *(const bf8_t*)(s1L + fm * 72 + k0 + quad * 8);
            bf8_t bh = *(const bf8_t*)(w2fh + col * 64 + k0 + quad * 8);
            bf8_t bl = *(const bf8_t*)(w2fl + col * 64 + k0 + quad * 8);
            acc = __builtin_amdgcn_mfma_f32_16x16x32_bf16(ah, bh, acc, 0, 0, 0);
            acc = __builtin_amdgcn_mfma_f32_16x16x32_bf16(ah, bl, acc, 0, 0, 0);
            acc = __builtin_amdgcn_mfma_f32_16x16x32_bf16(al, bh, acc, 0, 0, 0);
        }
#pragma unroll
        for (int r = 0; r < 4; ++r) s2sp[(quad * 4 + r) * 132 + col] = acc[r];
    }
    __syncthreads();

    // P3: combine2 -> split-bf16 to LDS (+ global when do_g)
    {
        int c4 = tid & 31, g = tid >> 5;
        float4 bse = *(float4*)&s2sp[g * 132 + c4 * 4];
        float4 wx = ((const float4*)W2)[c4];
        float4 wy = ((const float4*)(W2 + 128))[c4];
        float4 wz = ((const float4*)(W2 + 256))[c4];
        float4 m = make_float4(-1e30f, -1e30f, -1e30f, -1e30f);
#pragma unroll
        for (int k = 0; k < KNN; ++k) {
            int di = ((16 + g) * 8 + k) * 3;
            float dx = dspf[di + 0], dy = dspf[di + 1], dz = dspf[di + 2];
            float4 v;
            v.x = fmaf(dz, wz.x, fmaf(dy, wy.x, fmaf(dx, wx.x, bse.x)));
            v.y = fmaf(dz, wz.y, fmaf(dy, wy.y, fmaf(dx, wx.y, bse.y)));
            v.z = fmaf(dz, wz.z, fmaf(dy, wy.z, fmaf(dx, wx.z, bse.z)));
            v.w = fmaf(dz, wz.w, fmaf(dy, wy.w, fmaf(dx, wx.w, bse.w)));
            if (!FIRST) {
                v.x += g2r[k].x; v.y += g2r[k].y;
                v.z += g2r[k].z; v.w += g2r[k].w;
            }
            m.x = fmaxf(m.x, v.x); m.y = fmaxf(m.y, v.y);
            m.z = fmaxf(m.z, v.z); m.w = fmaxf(m.w, v.w);
        }
        ushort4 mh, ml;
        mh.x = f2b(m.x); ml.x = f2b(m.x - b2f(mh.x));
        mh.y = f2b(m.y); ml.y = f2b(m.y - b2f(mh.y));
        mh.z = f2b(m.z); ml.z = f2b(m.z - b2f(mh.z));
        mh.w = f2b(m.w); ml.w = f2b(m.w - b2f(mh.w));
        if (do_g) {
            *(ushort4*)&s2h[(row0 + g) * 128 + c4 * 4] = mh;
            *(ushort4*)&s2l[(row0 + g) * 128 + c4 * 4] = ml;
        }
        *(ushort4*)(s2H + g * 136 + c4 * 4) = mh;
        *(ushort4*)(s2L + g * 136 + c4 * 4) = ml;
    }
    __syncthreads();

    // G3 gathers prefetched (consumed in P5, hidden behind P4 MFMA)
    float4 g3r[2][KNN];
    {
        int c4 = tid & 63, g = tid >> 6;
        if (!FIRST) {
#pragma unroll
            for (int r = 0; r < 2; ++r)
#pragma unroll
                for (int k = 0; k < KNN; ++k)
                    g3r[r][k] = ((const float4*)G3p)[(bN + jssp[(32 + 2 * g + r) * 8 + k]) * 64 + c4];
        }
    }

    // P4: base3 = s2 @ W3f + b3 on MFMA (A from LDS bf16) -> s3b
    {
        int col0 = wv * 16 + fm, col1 = (wv + 8) * 16 + fm;
        float bz0 = b3[col0], bz1 = b3[col1];
        f4_t a0 = {bz0, bz0, bz0, bz0};
        f4_t a1 = {bz1, bz1, bz1, bz1};
#pragma unroll
        for (int k0 = 0; k0 < 128; k0 += 32) {
            bf8_t ah = *(const bf8_t*)(s2H + fm * 136 + k0 + quad * 8);
            bf8_t al = *(const bf8_t*)(s2L + fm * 136 + k0 + quad * 8);
            bf8_t b0h = *(const bf8_t*)(w3fh + col0 * 128 + k0 + quad * 8);
            bf8_t b0l = *(const bf8_t*)(w3fl + col0 * 128 + k0 + quad * 8);
            bf8_t b1h = *(const bf8_t*)(w3fh + col1 * 128 + k0 + quad * 8);
            bf8_t b1l = *(const bf8_t*)(w3fl + col1 * 128 + k0 + quad * 8);
            a0 = __builtin_amdgcn_mfma_f32_16x16x32_bf16(ah, b0h, a0, 0, 0, 0);
            a0 = __builtin_amdgcn_mfma_f32_16x16x32_bf16(ah, b0l, a0, 0, 0, 0);
            a0 = __builtin_amdgcn_mfma_f32_16x16x32_bf16(al, b0h, a0, 0, 0, 0);
            a1 = __builtin_amdgcn_mfma_f32_16x16x32_bf16(ah, b1h, a1, 0, 0, 0);
            a1 = __builtin_amdgcn_mfma_f32_16x16x32_bf16(ah, b1l, a1, 0, 0, 0);
            a1 = __builtin_amdgcn_mfma_f32_16x16x32_bf16(al, b1h, a1, 0, 0, 0);
        }
#pragma unroll
        for (int r = 0; r < 4; ++r) {
            s3bp[(quad * 4 + r) * 260 + col0] = a0[r];
            s3bp[(quad * 4 + r) * 260 + col1] = a1[r];
        }
    }
    __syncthreads();

    // P5: combine3 -> split-bf16 to global (when do_g); fp32 back into s3b
    {
        int c4 = tid & 63, g = tid >> 6;
        float4 wx = ((const float4*)W3)[c4];
        float4 wy = ((const float4*)(W3 + 256))[c4];
        float4 wz = ((const float4*)(W3 + 512))[c4];
#pragma unroll
        for (int r = 0; r < 2; ++r) {
            int p = 2 * g + r;
            float4 bse = *(float4*)&s3bp[p * 260 + c4 * 4];
            float4 m = make_float4(-1e30f, -1e30f, -1e30f, -1e30f);
#pragma unroll
            for (int k = 0; k < KNN; ++k) {
                int di = ((32 + p) * 8 + k) * 3;
                float dx = dspf[di + 0], dy = dspf[di + 1], dz = dspf[di + 2];
                float4 v;
                v.x = fmaf(dz, wz.x, fmaf(dy, wy.x, fmaf(dx, wx.x, bse.x)));
                v.y = fmaf(dz, wz.y, fmaf(dy, wy.y, fmaf(dx, wx.y, bse.y)));
                v.z = fmaf(dz, wz.z, fmaf(dy, wy.z, fmaf(dx, wx.z, bse.z)));
                v.w = fmaf(dz, wz.w, fmaf(dy, wy.w, fmaf(dx, wx.w, bse.w)));
                if (!FIRST) {
                    v.x += g3r[r][k].x; v.y += g3r[r][k].y;
                    v.z += g3r[r][k].z; v.w += g3r[r][k].w;
                }
                m.x = fmaxf(m.x, v.x); m.y = fmaxf(m.y, v.y);
                m.z = fmaxf(m.z, v.z); m.w = fmaxf(m.w, v.w);
            }
            *(float4*)&s3bp[p * 260 + c4 * 4] = m;   // in place (thread-owned)
            if (do_g) {
                ushort4 mh, ml;
                mh.x = f2b(m.x); ml.x = f2b(m.x - b2f(mh.x));
                mh.y = f2b(m.y); ml.y = f2b(m.y - b2f(mh.y));
                mh.z = f2b(m.z); ml.z = f2b(m.z - b2f(mh.z));
                mh.w = f2b(m.w); ml.w = f2b(m.w - b2f(mh.w));
                *(ushort4*)&s3h[(row0 + p) * 256 + c4 * 4] = mh;
                *(ushort4*)&s3l[(row0 + p) * 256 + c4 * 4] = ml;
            }
        }
    }

    // P6: head — h = relu(s3 @ Wm + bm) on MFMA (cvt from fp32 s3b), motion
    if (do_head) {
        __syncthreads();
        if (wv < 4) {
            int col = wv * 16 + fm;
            float bz = bm[col];
            f4_t acc = {bz, bz, bz, bz};
#pragma unroll
            for (int k0 = 0; k0 < 256; k0 += 32) {
                bf8_t ah, al; cvt8(&s3bp[fm * 260 + k0 + quad * 8], ah, al);
                bf8_t bh = *(const bf8_t*)(wmh + col * 256 + k0 + quad * 8);
                bf8_t bl = *(const bf8_t*)(wml + col * 256 + k0 + quad * 8);
                acc = __builtin_amdgcn_mfma_f32_16x16x32_bf16(ah, bh, acc, 0, 0, 0);
                acc = __builtin_amdgcn_mfma_f32_16x16x32_bf16(ah, bl, acc, 0, 0, 0);
                acc = __builtin_amdgcn_mfma_f32_16x16x32_bf16(al, bh, acc, 0, 0, 0);
            }
#pragma unroll
            for (int r = 0; r < 4; ++r)
                hsp[(quad * 4 + r) * 64 + col] = fmaxf(acc[r], 0.f);
        }
        __syncthreads();
        if (tid < PB * 3) {
            int p = tid / 3, d = tid % 3;
            float m = bl[d];
#pragma unroll 4
            for (int c = 0; c < 64; ++c)
                m = fmaf(hsp[p * 64 + c], Wl[c * 3 + d], m);
            const float* qp = xq + (long)b * xq_bs + (n0 + p) * 3;
            xnext[(long)b * xn_bs + (n0 + p) * 3 + d] = qp[d] + m;
        }
    }
}

// ---------------------------------------------------------------------------
// Tiled MFMA GEMM: 64 rows x 64 cols per block (4 waves x 16 rows), doubling
// block count vs the 128-row tile -> 896 blocks, better latency hiding.
// Same per-element accumulation order (bitwise-identical G).
// ---------------------------------------------------------------------------
template<int N>
__device__ __forceinline__ void gemmTile64(
        const ushort* __restrict__ Ah, const ushort* __restrict__ Al,
        const ushort* __restrict__ Bh, const ushort* __restrict__ Bl,
        float* __restrict__ G, int rb, int cb, int tid, ushort* lds) {
    const int row0 = rb * 64, c0 = cb * 64;
    ushort* ah = lds;
    ushort* al = lds + 64 * 40;
    ushort* bh = lds + 128 * 40;
    ushort* bl = lds + 192 * 40;
    const int wv = tid >> 6, lane = tid & 63;
    const int m = lane & 15, quad = lane >> 4;
    const int wm0 = wv * 16;
    const int lr = tid >> 2, ls = (tid & 3) * 8;

    f4_t acc[4];
#pragma unroll
    for (int ct = 0; ct < 4; ++ct) acc[ct] = (f4_t){0.f, 0.f, 0.f, 0.f};

    bf8_t pah, pal, pbh, pbl;
    pah = *(const bf8_t*)(Ah + (long)(row0 + lr) * N + ls);
    pal = *(const bf8_t*)(Al + (long)(row0 + lr) * N + ls);
    pbh = *(const bf8_t*)(Bh + (long)(c0 + lr) * N + ls);
    pbl = *(const bf8_t*)(Bl + (long)(c0 + lr) * N + ls);

    for (int k0 = 0; k0 < N; k0 += 32) {
        if (k0) __syncthreads();
        *(bf8_t*)(ah + lr * 40 + ls) = pah;
        *(bf8_t*)(al + lr * 40 + ls) = pal;
        *(bf8_t*)(bh + lr * 40 + ls) = pbh;
        *(bf8_t*)(bl + lr * 40 + ls) = pbl;
        __syncthreads();
        if (k0 + 32 < N) {
            int kn = k0 + 32;
            pah = *(const bf8_t*)(Ah + (long)(row0 + lr) * N + kn + ls);
            pal = *(const bf8_t*)(Al + (long)(row0 + lr) * N + kn + ls);
            pbh = *(const bf8_t*)(Bh + (long)(c0 + lr) * N + kn + ls);
            pbl = *(const bf8_t*)(Bl + (long)(c0 + lr) * N + kn + ls);
        }
        bf8_t a0h = *(const bf8_t*)(ah + (wm0 + m) * 40 + quad * 8);
        bf8_t a0l = *(const bf8_t*)(al + (wm0 + m) * 40 + quad * 8);
#pragma unroll
        for (int ct = 0; ct < 4; ++ct) {
            bf8_t bth = *(const bf8_t*)(bh + (ct * 16 + m) * 40 + quad * 8);
            bf8_t btl = *(const bf8_t*)(bl + (ct * 16 + m) * 40 + quad * 8);
            acc[ct] = __builtin_amdgcn_mfma_f32_16x16x32_bf16(a0h, bth, acc[ct], 0, 0, 0);
            acc[ct] = __builtin_amdgcn_mfma_f32_16x16x32_bf16(a0h, btl, acc[ct], 0, 0, 0);
            acc[ct] = __builtin_amdgcn_mfma_f32_16x16x32_bf16(a0l, bth, acc[ct], 0, 0, 0);
        }
    }
#pragma unroll
    for (int ct = 0; ct < 4; ++ct) {
        int col = c0 + ct * 16 + m;
#pragma unroll
        for (int r = 0; r < 4; ++r)
            G[(long)(row0 + wm0 + quad * 4 + r) * N + col] = acc[ct][r];
    }
}

// cell3: 512 blocks, cell2: 256, cell1: 128 — all XCD-affinity swizzled so
// rb tiles of batch b run on XCD b/2 (matching cells' producers/consumers).
__global__ __launch_bounds__(256) void gemmG_kernel(
        const ushort* __restrict__ s1h, const ushort* __restrict__ s1l,
        const ushort* __restrict__ s2h, const ushort* __restrict__ s2l,
        const ushort* __restrict__ s3h, const ushort* __restrict__ s3l,
        const ushort* __restrict__ w1h, const ushort* __restrict__ w1l,
        const ushort* __restrict__ w2h, const ushort* __restrict__ w2l,
        const ushort* __restrict__ w3h, const ushort* __restrict__ w3l,
        float* __restrict__ G1, float* __restrict__ G2,
        float* __restrict__ G3) {
    __shared__ ushort lds[256 * 40];
    int bx = blockIdx.x, tid = threadIdx.x;
    if (bx < 512) {
        int xcd = bx & 7, u = bx >> 3;             // u: 0..63
        int rb = xcd * 16 + (u & 15), cb = u >> 4; // rb 0..127, cb 0..3
        gemmTile64<256>(s3h, s3l, w3h, w3l, G3, rb, cb, tid, lds);
    } else if (bx < 768) {
        int v = bx - 512; int xcd = v & 7, u = v >> 3;   // u: 0..31
        int rb = xcd * 16 + (u & 15), cb = u >> 4;       // cb 0..1
        gemmTile64<128>(s2h, s2l, w2h, w2l, G2, rb, cb, tid, lds);
    } else {
        int v = bx - 768; int xcd = v & 7, u = v >> 3;   // u: 0..15
        gemmTile64<64>(s1h, s1l, w1h, w1l, G1, xcd * 16 + u, 0, tid, lds);
    }
}

extern "C" void kernel_launch(void* const* d_in, const int* in_sizes, int n_in,
                              void* d_out, int out_size, void* d_ws, size_t ws_size,
                              hipStream_t stream) {
    const float* frames = (const float*)d_in[0];
    const float* W1 = (const float*)d_in[1]; const float* b1 = (const float*)d_in[2];
    const float* W2 = (const float*)d_in[3]; const float* b2 = (const float*)d_in[4];
    const float* W3 = (const float*)d_in[5]; const float* b3 = (const float*)d_in[6];
    const float* Wm = (const float*)d_in[7]; const float* bm = (const float*)d_in[8];
    const float* Wl = (const float*)d_in[9]; const float* bl = (const float*)d_in[10];
    float* out = (float*)d_out;

    const long M = (long)BB * NN;    // 8192
    float* ws = (float*)d_ws;
    float* G1b = ws; ws += M * 64;
    float* G2b = ws; ws += M * 128;
    float* G3b = ws; ws += M * 256;
    ushort* us = (ushort*)ws;
    ushort* s1h = us; us += M * 64;   ushort* s1l = us; us += M * 64;
    ushort* s2h = us; us += M * 128;  ushort* s2l = us; us += M * 128;
    ushort* s3h = us; us += M * 256;  ushort* s3l = us; us += M * 256;
    ushort* w1h = us; us += 4096;     ushort* w1l = us; us += 4096;
    ushort* w2h = us; us += 16384;    ushort* w2l = us; us += 16384;
    ushort* w3h = us; us += 65536;    ushort* w3l = us; us += 65536;
    ushort* w2fh = us; us += 8192;    ushort* w2fl = us; us += 8192;
    ushort* w3fh = us; us += 32768;   ushort* w3fl = us; us += 32768;
    ushort* wmh = us; us += 16384;    ushort* wml = us; us += 16384;
    const long BNK = M * KNN;
    int* ip = (int*)us;
    int* idx1w = ip; ip += 7 * BNK;
    int* idx2w = ip; ip += 7 * BNK;
    int* idx3w = ip; ip += 7 * BNK;

    double ra = 4.0 + 1e-6, rb = 8.0 + 1e-6, rc = 12.0 + 1e-6;
    float r2a = (float)(ra * ra), r2b = (float)(rb * rb), r2c = (float)(rc * rc);

    const int FB = SEQ * NN * 3;
    const int OB = 6 * NN * 3;

    convW_kernel<<<560, 256, 0, stream>>>(W1, W2, W3, Wm,
                                          w1h, w1l, w2h, w2l, w3h, w3l,
                                          w2fh, w2fl, w3fh, w3fl, wmh, wml);
    knn_kernel<<<dim3(NN / QB, BB, 7), 256, 0, stream>>>(
        frames, FB, nullptr, 0, idx1w, idx2w, idx3w, r2a, r2b, r2c, 1);

    for (int t = 0; t < SEQ; ++t) {
        const float* xq; int xq_bs;
        const float* xs; int xs_bs;
        if (t < 6)       { xq = frames + (long)t * NN * 3;        xq_bs = FB; }
        else if (t == 6) { xq = frames + 5L * NN * 3;             xq_bs = FB; }
        else             { xq = out + (long)(t - 7) * NN * 3;     xq_bs = OB; }
        if (t == 0)      { xs = xq;                               xs_bs = xq_bs; }
        else if (t <= 6) { xs = frames + (long)(t - 1) * NN * 3;  xs_bs = FB; }
        else if (t == 7) { xs = frames + 5L * NN * 3;             xs_bs = FB; }
        else             { xs = out + (long)(t - 8) * NN * 3;     xs_bs = OB; }

        int slot = (t <= 6) ? t : 0;    // t>=7 reuses slot 0
        int* i1 = idx1w + slot * BNK;
        int* i2 = idx2w + slot * BNK;
        int* i3 = idx3w + slot * BNK;

        if (t >= 7)
            knn_kernel<<<dim3(NN / QB, BB, 1), 256, 0, stream>>>(
                xq, xq_bs, xs, xs_bs, i1, i2, i3, r2a, r2b, r2c, 0);

        int do_head = (t >= 6);
        int do_g = (t < SEQ - 1);
        float* xnext = do_head ? out + (long)(t - 6) * NN * 3 : nullptr;

        if (t == 0)
            cells_kernel<true><<<BB * NN / PB, 512, 0, stream>>>(
                xq, xq_bs, xs, xs_bs, i1, i2, i3,
                G1b, G2b, G3b, s1h, s1l, s2h, s2l, s3h, s3l,
                W1, b1, W2, b2, W3, b3,
                w2fh, w2fl, w3fh, w3fl, wmh, wml, bm,
                Wl, bl, xnext, OB, do_head, do_g);
        else
            cells_kernel<false><<<BB * NN / PB, 512, 0, stream>>>(
                xq, xq_bs, xs, xs_bs, i1, i2, i3,
                G1b, G2b, G3b, s1h, s1l, s2h, s2l, s3h, s3l,
                W1, b1, W2, b2, W3, b3,
                w2fh, w2fl, w3fh, w3fl, wmh, wml, bm,
                Wl, bl, xnext, OB, do_head, do_g);

        // G for step t+1 on the matrix pipe
        if (t < SEQ - 1)
            gemmG_kernel<<<896, 256, 0, stream>>>(
                s1h, s1l, s2h, s2l, s3h, s3l,
                w1h, w1l, w2h, w2l, w3h, w3l,
                G1b, G2b, G3b);
    }
}